// Round 1
// baseline (1512.976 us; speedup 1.0000x reference)
//
#include <hip/hip_runtime.h>
#include <math.h>

// Problem constants (from reference): DM=512, DS=16, K=4, EXPAND=1
#define DMc   512
#define DIc   512
#define DSc   16
#define KCc   4
#define DTRc  32          // (512+15)//16
#define NXDc  64          // DTR + 2*DS
#define LLEN  2048
#define BBc   4
#define BLT   (BBc*LLEN)  // 8192

__device__ __forceinline__ float sigmoidf_(float x) { return 1.f / (1.f + __expf(-x)); }

// ---------------------------------------------------------------------------
// C[M,N] = A[M,K] * B[N,K]^T    (both operands K-contiguous)
// 64x64 tile, BK=16, 256 threads, 4x4 micro-tile per thread.
// EPI==1: clip to [-1000,1000], NaN->0 (final output epilogue)
// ---------------------------------------------------------------------------
template<int EPI>
__global__ __launch_bounds__(256) void gemm_bt(const float* __restrict__ A,
                                               const float* __restrict__ Bw,
                                               float* __restrict__ C,
                                               int M, int N, int Kd)
{
    __shared__ float As[16][68];   // +4 pad keeps 16B alignment, breaks bank stride
    __shared__ float Bs[16][68];
    const int tid  = threadIdx.x;
    const int tx   = tid & 15;     // -> N
    const int ty   = tid >> 4;     // -> M
    const int arow = tid >> 2;     // 0..63 : row within tile for staging
    const int akq  = (tid & 3) << 2; // k offset 0,4,8,12

    const float* Ab = A  + (size_t)(blockIdx.y * 64 + arow) * Kd + akq;
    const float* Bb = Bw + (size_t)(blockIdx.x * 64 + arow) * Kd + akq;

    float acc[4][4] = {};

    for (int k0 = 0; k0 < Kd; k0 += 16) {
        float4 av = *(const float4*)(Ab + k0);
        float4 bv = *(const float4*)(Bb + k0);
        __syncthreads();
        As[akq + 0][arow] = av.x; As[akq + 1][arow] = av.y;
        As[akq + 2][arow] = av.z; As[akq + 3][arow] = av.w;
        Bs[akq + 0][arow] = bv.x; Bs[akq + 1][arow] = bv.y;
        Bs[akq + 2][arow] = bv.z; Bs[akq + 3][arow] = bv.w;
        __syncthreads();
#pragma unroll
        for (int k = 0; k < 16; ++k) {
            float4 a = *(const float4*)&As[k][ty << 2];
            float4 b = *(const float4*)&Bs[k][tx << 2];
            float ar[4] = {a.x, a.y, a.z, a.w};
            float br[4] = {b.x, b.y, b.z, b.w};
#pragma unroll
            for (int i = 0; i < 4; ++i)
#pragma unroll
                for (int j = 0; j < 4; ++j)
                    acc[i][j] += ar[i] * br[j];
        }
    }

#pragma unroll
    for (int i = 0; i < 4; ++i) {
        float v0 = acc[i][0], v1 = acc[i][1], v2 = acc[i][2], v3 = acc[i][3];
        if (EPI) {
            v0 = (v0 != v0) ? 0.f : fminf(fmaxf(v0, -1000.f), 1000.f);
            v1 = (v1 != v1) ? 0.f : fminf(fmaxf(v1, -1000.f), 1000.f);
            v2 = (v2 != v2) ? 0.f : fminf(fmaxf(v2, -1000.f), 1000.f);
            v3 = (v3 != v3) ? 0.f : fminf(fmaxf(v3, -1000.f), 1000.f);
        }
        float4 v = make_float4(v0, v1, v2, v3);
        *(float4*)(C + (size_t)(blockIdx.y * 64 + (ty << 2) + i) * N
                     + blockIdx.x * 64 + (tx << 2)) = v;
    }
}

// ---------------------------------------------------------------------------
// Depthwise causal conv (K=4) + bias + SiLU on the first DI lanes of xz.
// xz: [B*L, 1024]  ->  xc: [B*L, 512]
// ---------------------------------------------------------------------------
__global__ __launch_bounds__(256) void conv_silu_kernel(const float* __restrict__ xz,
                                                        const float* __restrict__ cw,
                                                        const float* __restrict__ cb,
                                                        float* __restrict__ xc)
{
    int gid = blockIdx.x * 256 + threadIdx.x;       // over B*L*DI
    int d = gid & (DIc - 1);
    int l = (gid >> 9) & (LLEN - 1);
    int b = gid >> 20;
    float s = cb[d];
#pragma unroll
    for (int k = 0; k < KCc; ++k) {
        int ls = l + k - (KCc - 1);
        if (ls >= 0)
            s += xz[((size_t)(b * LLEN + ls) << 10) + d] * cw[d * KCc + k];
    }
    xc[gid] = s * sigmoidf_(s);
}

// ---------------------------------------------------------------------------
// x_dbl[row, r] = dot(xc[row, :512], W_xproj[r, :512])   r in [0,64)
// one block (64 threads) per row
// ---------------------------------------------------------------------------
__global__ __launch_bounds__(64) void xdbl_kernel(const float* __restrict__ xc,
                                                  const float* __restrict__ Wx,
                                                  float* __restrict__ xdbl)
{
    int row = blockIdx.x;
    int r   = threadIdx.x;
    const float4* xr = (const float4*)(xc + (size_t)row * DIc);
    const float4* wr = (const float4*)(Wx + (size_t)r * DIc);
    float s = 0.f;
#pragma unroll 4
    for (int i = 0; i < DIc / 4; ++i) {
        float4 a = xr[i], w = wr[i];
        s += a.x * w.x + a.y * w.y + a.z * w.z + a.w * w.w;
    }
    xdbl[(size_t)row * NXDc + r] = s;
}

// ---------------------------------------------------------------------------
// dt[row, d] = softplus( dot(xdbl[row, :32], W_dt[d, :32]) + b_dt[d] )
// ---------------------------------------------------------------------------
__global__ __launch_bounds__(256) void dt_kernel(const float* __restrict__ xdbl,
                                                 const float* __restrict__ Wdt,
                                                 const float* __restrict__ bdt,
                                                 float* __restrict__ dt)
{
    int gid = blockIdx.x * 256 + threadIdx.x;       // over B*L*DI
    int d   = gid & (DIc - 1);
    int row = gid >> 9;
    const float4* xr = (const float4*)(xdbl + (size_t)row * NXDc);
    const float4* wr = (const float4*)(Wdt + (size_t)d * DTRc);
    float s = bdt[d];
#pragma unroll
    for (int i = 0; i < DTRc / 4; ++i) {
        float4 a = xr[i], w = wr[i];
        s += a.x * w.x + a.y * w.y + a.z * w.z + a.w * w.w;
    }
    // softplus, numerically stable
    float sp = fmaxf(s, 0.f) + log1pf(__expf(-fabsf(s)));
    dt[gid] = sp;
}

// ---------------------------------------------------------------------------
// Selective scan. One thread per (b, d) channel, h[16] in registers.
// dty: on input dt[b,l,d]; y written in place (same per-thread index,
// read-before-write within the thread).
// y[b,l,d] = (sum_s h_s * C_s + xc*D) * silu(z)
// ---------------------------------------------------------------------------
__global__ __launch_bounds__(256) void scan_kernel(float* __restrict__ dty,
                                                   const float* __restrict__ xc,
                                                   const float* __restrict__ xdbl,
                                                   const float* __restrict__ xz,
                                                   const float* __restrict__ A_log,
                                                   const float* __restrict__ Dp)
{
    int b = blockIdx.x >> 1;                       // 2 blocks per batch
    int d = ((blockIdx.x & 1) << 8) + threadIdx.x; // 0..511

    float A[DSc];
#pragma unroll
    for (int s = 0; s < DSc; ++s) A[s] = -__expf(A_log[d * DSc + s]);
    float Dv = Dp[d];

    float h[DSc];
#pragma unroll
    for (int s = 0; s < DSc; ++s) h[s] = 0.f;

    float*       dtp = dty + (size_t)b * LLEN * DIc + d;
    const float* xcp = xc  + (size_t)b * LLEN * DIc + d;
    const float* zp  = xz  + (size_t)b * LLEN * 1024 + DIc + d;
    const float* xdp = xdbl + (size_t)b * LLEN * NXDc;

    for (int t = 0; t < LLEN; ++t) {
        float dtv = dtp[(size_t)t * DIc];
        float xcv = xcp[(size_t)t * DIc];
        float zv  = zp[(size_t)t * 1024];
        const float* xd = xdp + (size_t)t * NXDc;
        float dBx = dtv * xcv;
        float acc = 0.f;
#pragma unroll
        for (int s = 0; s < DSc; ++s) {
            float Bv = xd[DTRc + s];
            float Cv = xd[DTRc + DSc + s];
            float dA = __expf(dtv * A[s]);
            h[s] = dA * h[s] + dBx * Bv;
            acc += h[s] * Cv;
        }
        float yv = (acc + xcv * Dv) * (zv * sigmoidf_(zv));
        dtp[(size_t)t * DIc] = yv;   // y in place of dt
    }
}

// ---------------------------------------------------------------------------
extern "C" void kernel_launch(void* const* d_in, const int* in_sizes, int n_in,
                              void* d_out, int out_size, void* d_ws, size_t ws_size,
                              hipStream_t stream)
{
    const float* x      = (const float*)d_in[0];
    const float* W_in   = (const float*)d_in[1];
    const float* conv_w = (const float*)d_in[2];
    const float* conv_b = (const float*)d_in[3];
    const float* W_xp   = (const float*)d_in[4];
    const float* W_dt   = (const float*)d_in[5];
    const float* b_dt   = (const float*)d_in[6];
    const float* A_log  = (const float*)d_in[7];
    const float* D_par  = (const float*)d_in[8];
    const float* W_out  = (const float*)d_in[9];
    float* out = (float*)d_out;

    float* ws   = (float*)d_ws;
    float* xz   = ws;                                   // [8192,1024]
    float* xc   = xz + (size_t)BLT * 1024;              // [8192,512]
    float* xdbl = xc + (size_t)BLT * DIc;               // [8192,64]
    float* dty  = xdbl + (size_t)BLT * NXDc;            // [8192,512] dt then y

    // 1. xz = x @ W_in^T      (M=8192, N=1024, K=512)
    gemm_bt<0><<<dim3(1024 / 64, BLT / 64), 256, 0, stream>>>(x, W_in, xz, BLT, 1024, DMc);

    // 2. depthwise causal conv + SiLU -> xc
    conv_silu_kernel<<<(BLT * DIc) / 256, 256, 0, stream>>>(xz, conv_w, conv_b, xc);

    // 3. x_dbl = xc @ W_xproj^T   (N=64, K=512)
    xdbl_kernel<<<BLT, 64, 0, stream>>>(xc, W_xp, xdbl);

    // 4. dt = softplus(x_dbl[:, :32] @ W_dt^T + b_dt)
    dt_kernel<<<(BLT * DIc) / 256, 256, 0, stream>>>(xdbl, W_dt, b_dt, dty);

    // 5. selective scan (y written in place of dt)
    scan_kernel<<<BBc * (DIc / 256), 256, 0, stream>>>(dty, xc, xdbl, xz, A_log, D_par);

    // 6. out = clip(y @ W_out^T)  (M=8192, N=512, K=512)
    gemm_bt<1><<<dim3(DMc / 64, BLT / 64), 256, 0, stream>>>(dty, W_out, out, BLT, DMc, DMc);
}

// Round 2
// 472.635 us; speedup vs baseline: 3.2012x; 3.2012x over previous
//
#include <hip/hip_runtime.h>
#include <math.h>

// Problem constants (from reference): DM=512, DS=16, K=4, EXPAND=1
#define DMc   512
#define DIc   512
#define DSc   16
#define KCc   4
#define DTRc  32          // (512+15)//16
#define NXDc  64          // DTR + 2*DS
#define LLEN  2048
#define BBc   4
#define BLT   (BBc*LLEN)  // 8192

// chunked scan config
#define NCH   64          // chunks per sequence
#define CLEN  (LLEN/NCH)  // 32

__device__ __forceinline__ float sigmoidf_(float x) { return 1.f / (1.f + __expf(-x)); }

// ---------------------------------------------------------------------------
// C[M,N] = A[M,K] * B[N,K]^T    (both operands K-contiguous)
// 64x64 tile, BK=16, 256 threads, 4x4 micro-tile per thread.
// EPI==1: clip to [-1000,1000], NaN->0 (final output epilogue)
// ---------------------------------------------------------------------------
template<int EPI>
__global__ __launch_bounds__(256) void gemm_bt(const float* __restrict__ A,
                                               const float* __restrict__ Bw,
                                               float* __restrict__ C,
                                               int M, int N, int Kd)
{
    __shared__ float As[16][68];
    __shared__ float Bs[16][68];
    const int tid  = threadIdx.x;
    const int tx   = tid & 15;     // -> N
    const int ty   = tid >> 4;     // -> M
    const int arow = tid >> 2;     // 0..63 : row within tile for staging
    const int akq  = (tid & 3) << 2; // k offset 0,4,8,12

    const float* Ab = A  + (size_t)(blockIdx.y * 64 + arow) * Kd + akq;
    const float* Bb = Bw + (size_t)(blockIdx.x * 64 + arow) * Kd + akq;

    float acc[4][4] = {};

    for (int k0 = 0; k0 < Kd; k0 += 16) {
        float4 av = *(const float4*)(Ab + k0);
        float4 bv = *(const float4*)(Bb + k0);
        __syncthreads();
        As[akq + 0][arow] = av.x; As[akq + 1][arow] = av.y;
        As[akq + 2][arow] = av.z; As[akq + 3][arow] = av.w;
        Bs[akq + 0][arow] = bv.x; Bs[akq + 1][arow] = bv.y;
        Bs[akq + 2][arow] = bv.z; Bs[akq + 3][arow] = bv.w;
        __syncthreads();
#pragma unroll
        for (int k = 0; k < 16; ++k) {
            float4 a = *(const float4*)&As[k][ty << 2];
            float4 b = *(const float4*)&Bs[k][tx << 2];
            float ar[4] = {a.x, a.y, a.z, a.w};
            float br[4] = {b.x, b.y, b.z, b.w};
#pragma unroll
            for (int i = 0; i < 4; ++i)
#pragma unroll
                for (int j = 0; j < 4; ++j)
                    acc[i][j] += ar[i] * br[j];
        }
    }

#pragma unroll
    for (int i = 0; i < 4; ++i) {
        float v0 = acc[i][0], v1 = acc[i][1], v2 = acc[i][2], v3 = acc[i][3];
        if (EPI) {
            v0 = (v0 != v0) ? 0.f : fminf(fmaxf(v0, -1000.f), 1000.f);
            v1 = (v1 != v1) ? 0.f : fminf(fmaxf(v1, -1000.f), 1000.f);
            v2 = (v2 != v2) ? 0.f : fminf(fmaxf(v2, -1000.f), 1000.f);
            v3 = (v3 != v3) ? 0.f : fminf(fmaxf(v3, -1000.f), 1000.f);
        }
        float4 v = make_float4(v0, v1, v2, v3);
        *(float4*)(C + (size_t)(blockIdx.y * 64 + (ty << 2) + i) * N
                     + blockIdx.x * 64 + (tx << 2)) = v;
    }
}

// ---------------------------------------------------------------------------
// Depthwise causal conv (K=4) + bias + SiLU on the first DI lanes of xz.
// ---------------------------------------------------------------------------
__global__ __launch_bounds__(256) void conv_silu_kernel(const float* __restrict__ xz,
                                                        const float* __restrict__ cw,
                                                        const float* __restrict__ cb,
                                                        float* __restrict__ xc)
{
    int gid = blockIdx.x * 256 + threadIdx.x;       // over B*L*DI
    int d = gid & (DIc - 1);
    int l = (gid >> 9) & (LLEN - 1);
    int b = gid >> 20;
    float s = cb[d];
#pragma unroll
    for (int k = 0; k < KCc; ++k) {
        int ls = l + k - (KCc - 1);
        if (ls >= 0)
            s += xz[((size_t)(b * LLEN + ls) << 10) + d] * cw[d * KCc + k];
    }
    xc[gid] = s * sigmoidf_(s);
}

// ---------------------------------------------------------------------------
// x_dbl[row, r] = dot(xc[row, :512], W_xproj[r, :512])   r in [0,64)
// ---------------------------------------------------------------------------
__global__ __launch_bounds__(64) void xdbl_kernel(const float* __restrict__ xc,
                                                  const float* __restrict__ Wx,
                                                  float* __restrict__ xdbl)
{
    int row = blockIdx.x;
    int r   = threadIdx.x;
    const float4* xr = (const float4*)(xc + (size_t)row * DIc);
    const float4* wr = (const float4*)(Wx + (size_t)r * DIc);
    float s = 0.f;
#pragma unroll 4
    for (int i = 0; i < DIc / 4; ++i) {
        float4 a = xr[i], w = wr[i];
        s += a.x * w.x + a.y * w.y + a.z * w.z + a.w * w.w;
    }
    xdbl[(size_t)row * NXDc + r] = s;
}

// ---------------------------------------------------------------------------
// dt[row, d] = softplus( dot(xdbl[row, :32], W_dt[d, :32]) + b_dt[d] )
// ---------------------------------------------------------------------------
__global__ __launch_bounds__(256) void dt_kernel(const float* __restrict__ xdbl,
                                                 const float* __restrict__ Wdt,
                                                 const float* __restrict__ bdt,
                                                 float* __restrict__ dt)
{
    int gid = blockIdx.x * 256 + threadIdx.x;       // over B*L*DI
    int d   = gid & (DIc - 1);
    int row = gid >> 9;
    const float4* xr = (const float4*)(xdbl + (size_t)row * NXDc);
    const float4* wr = (const float4*)(Wdt + (size_t)d * DTRc);
    float s = bdt[d];
#pragma unroll
    for (int i = 0; i < DTRc / 4; ++i) {
        float4 a = xr[i], w = wr[i];
        s += a.x * w.x + a.y * w.y + a.z * w.z + a.w * w.w;
    }
    float sp = fmaxf(s, 0.f) + log1pf(__expf(-fabsf(s)));
    dt[gid] = sp;
}

// ---------------------------------------------------------------------------
// Chunked parallel scan. The recurrence h[t] = dA[t]*h[t-1] + dBu[t] is
// linear; chunk decay = exp(A[s] * sum(dt over chunk)).
//
// Chunk-state buffers are overlaid on the DEAD x-half of the xz buffer
// (first 512 of 1024 cols are unused after conv_silu):
//   h_end/h_in (b,c,s,d): xz[ ((b*NCH+c)*DSc + s) * 1024 + d ]   rows 0..4095
//   Sdt        (b,c,d)  : xz[ (4096 + b*NCH + c)  * 1024 + d ]   rows 4096..4351
// ---------------------------------------------------------------------------
__device__ __forceinline__ size_t hend_off(int b, int c, int s, int d) {
    return ((size_t)((b * NCH + c) * DSc + s) << 10) + d;
}
__device__ __forceinline__ size_t sdt_off(int b, int c, int d) {
    return ((size_t)(4096 + b * NCH + c) << 10) + d;
}

// Phase 1: per-(b,chunk,d) local scan with h_in = 0; emits h_end[16] and Sdt.
__global__ __launch_bounds__(256) void scan_phase1(const float* __restrict__ dty,
                                                   const float* __restrict__ xc,
                                                   const float* __restrict__ xdbl,
                                                   float* __restrict__ xzbuf,
                                                   const float* __restrict__ A_log)
{
    int half = blockIdx.x & 1;
    int c    = (blockIdx.x >> 1) & (NCH - 1);
    int b    = blockIdx.x >> 7;
    int d    = (half << 8) + threadIdx.x;

    float A[DSc];
#pragma unroll
    for (int s = 0; s < DSc; ++s) A[s] = -__expf(A_log[d * DSc + s]);

    float h[DSc];
#pragma unroll
    for (int s = 0; s < DSc; ++s) h[s] = 0.f;
    float Sdt = 0.f;

    int row0 = b * LLEN + c * CLEN;
    for (int t = 0; t < CLEN; ++t) {
        int row = row0 + t;
        float dtv = dty[((size_t)row << 9) + d];
        float xcv = xc[((size_t)row << 9) + d];
        Sdt += dtv;
        float dBx = dtv * xcv;
        const float* xd = xdbl + (size_t)row * NXDc;
#pragma unroll
        for (int s = 0; s < DSc; ++s)
            h[s] = __expf(dtv * A[s]) * h[s] + dBx * xd[DTRc + s];
    }
#pragma unroll
    for (int s = 0; s < DSc; ++s) xzbuf[hend_off(b, c, s, d)] = h[s];
    xzbuf[sdt_off(b, c, d)] = Sdt;
}

// Phase 2: per-(b,d) sequential combine over chunks; h_in overwrites h_end.
__global__ __launch_bounds__(256) void scan_phase2(float* __restrict__ xzbuf,
                                                   const float* __restrict__ A_log)
{
    int b = blockIdx.x >> 1;
    int d = ((blockIdx.x & 1) << 8) + threadIdx.x;

    float A[DSc];
#pragma unroll
    for (int s = 0; s < DSc; ++s) A[s] = -__expf(A_log[d * DSc + s]);

    float h[DSc];
#pragma unroll
    for (int s = 0; s < DSc; ++s) h[s] = 0.f;

    for (int c = 0; c < NCH; ++c) {
        float Sdt = xzbuf[sdt_off(b, c, d)];
#pragma unroll
        for (int s = 0; s < DSc; ++s) {
            size_t o = hend_off(b, c, s, d);
            float he = xzbuf[o];          // read h_end
            xzbuf[o] = h[s];              // write h_in (state before chunk c)
            h[s] = __expf(A[s] * Sdt) * h[s] + he;
        }
    }
}

// Phase 3: per-(b,chunk,d) re-scan from true h_in, write gated y over dt.
__global__ __launch_bounds__(256) void scan_phase3(float* __restrict__ dty,
                                                   const float* __restrict__ xc,
                                                   const float* __restrict__ xdbl,
                                                   const float* __restrict__ xzbuf,
                                                   const float* __restrict__ A_log,
                                                   const float* __restrict__ Dp)
{
    int half = blockIdx.x & 1;
    int c    = (blockIdx.x >> 1) & (NCH - 1);
    int b    = blockIdx.x >> 7;
    int d    = (half << 8) + threadIdx.x;

    float A[DSc];
#pragma unroll
    for (int s = 0; s < DSc; ++s) A[s] = -__expf(A_log[d * DSc + s]);
    float Dv = Dp[d];

    float h[DSc];
#pragma unroll
    for (int s = 0; s < DSc; ++s) h[s] = xzbuf[hend_off(b, c, s, d)];  // h_in

    int row0 = b * LLEN + c * CLEN;
    for (int t = 0; t < CLEN; ++t) {
        int row = row0 + t;
        float dtv = dty[((size_t)row << 9) + d];
        float xcv = xc[((size_t)row << 9) + d];
        float zv  = xzbuf[((size_t)row << 10) + DIc + d];
        float dBx = dtv * xcv;
        const float* xd = xdbl + (size_t)row * NXDc;
        float acc = 0.f;
#pragma unroll
        for (int s = 0; s < DSc; ++s) {
            float dA = __expf(dtv * A[s]);
            h[s] = dA * h[s] + dBx * xd[DTRc + s];
            acc += h[s] * xd[DTRc + DSc + s];
        }
        float yv = (acc + xcv * Dv) * (zv * sigmoidf_(zv));
        dty[((size_t)row << 9) + d] = yv;
    }
}

// ---------------------------------------------------------------------------
extern "C" void kernel_launch(void* const* d_in, const int* in_sizes, int n_in,
                              void* d_out, int out_size, void* d_ws, size_t ws_size,
                              hipStream_t stream)
{
    const float* x      = (const float*)d_in[0];
    const float* W_in   = (const float*)d_in[1];
    const float* conv_w = (const float*)d_in[2];
    const float* conv_b = (const float*)d_in[3];
    const float* W_xp   = (const float*)d_in[4];
    const float* W_dt   = (const float*)d_in[5];
    const float* b_dt   = (const float*)d_in[6];
    const float* A_log  = (const float*)d_in[7];
    const float* D_par  = (const float*)d_in[8];
    const float* W_out  = (const float*)d_in[9];
    float* out = (float*)d_out;

    float* ws   = (float*)d_ws;
    float* xz   = ws;                                   // [8192,1024]
    float* xc   = xz + (size_t)BLT * 1024;              // [8192,512]
    float* xdbl = xc + (size_t)BLT * DIc;               // [8192,64]
    float* dty  = xdbl + (size_t)BLT * NXDc;            // [8192,512] dt then y

    // 1. xz = x @ W_in^T      (M=8192, N=1024, K=512)
    gemm_bt<0><<<dim3(1024 / 64, BLT / 64), 256, 0, stream>>>(x, W_in, xz, BLT, 1024, DMc);

    // 2. depthwise causal conv + SiLU -> xc
    conv_silu_kernel<<<(BLT * DIc) / 256, 256, 0, stream>>>(xz, conv_w, conv_b, xc);

    // 3. x_dbl = xc @ W_xproj^T   (N=64, K=512)
    xdbl_kernel<<<BLT, 64, 0, stream>>>(xc, W_xp, xdbl);

    // 4. dt = softplus(x_dbl[:, :32] @ W_dt^T + b_dt)
    dt_kernel<<<(BLT * DIc) / 256, 256, 0, stream>>>(xdbl, W_dt, b_dt, dty);

    // 5. chunked parallel scan (y written in place of dt)
    scan_phase1<<<BBc * NCH * 2, 256, 0, stream>>>(dty, xc, xdbl, xz, A_log);
    scan_phase2<<<BBc * 2, 256, 0, stream>>>(xz, A_log);
    scan_phase3<<<BBc * NCH * 2, 256, 0, stream>>>(dty, xc, xdbl, xz, A_log, D_par);

    // 6. out = clip(y @ W_out^T)  (M=8192, N=512, K=512)
    gemm_bt<1><<<dim3(DMc / 64, BLT / 64), 256, 0, stream>>>(dty, W_out, out, BLT, DMc, DMc);
}

// Round 3
// 339.720 us; speedup vs baseline: 4.4536x; 1.3912x over previous
//
#include <hip/hip_runtime.h>
#include <math.h>

// Problem constants (from reference): DM=512, DS=16, K=4, EXPAND=1
#define DMc   512
#define DIc   512
#define DSc   16
#define KCc   4
#define DTRc  32          // (512+15)//16
#define NXDc  64          // DTR + 2*DS
#define LLEN  2048
#define BBc   4
#define BLT   (BBc*LLEN)  // 8192

// chunked scan config
#define NCH   64          // chunks per sequence
#define CLEN  (LLEN/NCH)  // 32

typedef __attribute__((ext_vector_type(8))) short short8;
typedef __attribute__((ext_vector_type(8))) unsigned short ushort8;
typedef __attribute__((ext_vector_type(4))) float f32x4;

__device__ __forceinline__ float sigmoidf_(float x) { return 1.f / (1.f + __expf(-x)); }

// round-to-nearest-even f32 -> bf16 bits
__device__ __forceinline__ unsigned short f2bf(float x) {
    unsigned int u = __float_as_uint(x);
    u = (u + 0x7FFFu + ((u >> 16) & 1u)) >> 16;
    return (unsigned short)u;
}

// ---------------------------------------------------------------------------
// f32 -> bf16 elementwise (8 elems/thread), n8 = n/8
// ---------------------------------------------------------------------------
__global__ __launch_bounds__(256) void f32_to_bf16_kernel(const float* __restrict__ in,
                                                          unsigned short* __restrict__ out,
                                                          int n8)
{
    int i = blockIdx.x * 256 + threadIdx.x;
    if (i >= n8) return;
    float4 a = ((const float4*)in)[2 * i];
    float4 b = ((const float4*)in)[2 * i + 1];
    ushort8 o;
    o[0] = f2bf(a.x); o[1] = f2bf(a.y); o[2] = f2bf(a.z); o[3] = f2bf(a.w);
    o[4] = f2bf(b.x); o[5] = f2bf(b.y); o[6] = f2bf(b.z); o[7] = f2bf(b.w);
    ((ushort8*)out)[i] = o;
}

// ---------------------------------------------------------------------------
// bf16 MFMA GEMM: C[M,N] = A[M,K] * B[N,K]^T, f32 accumulate/output.
// 128x128 tile, BK=32, 256 threads = 4 waves (2x2), 4x4 16x16 frags/wave.
// LDS row pitch 40 shorts (80 B): 16B-aligned, spreads banks (<=2-way).
// EPI==1: clip to [-1000,1000], NaN->0.
// ---------------------------------------------------------------------------
template<int EPI>
__global__ __launch_bounds__(256) void gemm_mfma(const unsigned short* __restrict__ A,
                                                 const unsigned short* __restrict__ Bw,
                                                 float* __restrict__ C,
                                                 int M, int N, int Kd)
{
    __shared__ short As[128][40];
    __shared__ short Bs[128][40];
    const int tid  = threadIdx.x;
    const int lane = tid & 63;
    const int wv   = tid >> 6;
    const int wr   = wv >> 1;          // wave row (0..1)
    const int wc   = wv & 1;           // wave col (0..1)
    const int fr   = lane & 15;        // fragment row within 16
    const int fq   = lane >> 4;        // k-quarter (0..3)

    const int rowA0 = blockIdx.y * 128;
    const int rowB0 = blockIdx.x * 128;

    // staging map: idx = tid + i*256 in [0,512): row = idx>>2, seg = idx&3 (8 bf16 each)
    const int r0 = tid >> 2,        s0 = (tid & 3) << 3;
    const int r1 = (tid + 256) >> 2, s1 = s0;   // (tid+256)&3 == tid&3

    f32x4 acc[4][4];
#pragma unroll
    for (int m = 0; m < 4; ++m)
#pragma unroll
        for (int n = 0; n < 4; ++n) acc[m][n] = (f32x4){0.f, 0.f, 0.f, 0.f};

    for (int k0 = 0; k0 < Kd; k0 += 32) {
        short8 a0 = *(const short8*)(A  + (size_t)(rowA0 + r0) * Kd + k0 + s0);
        short8 a1 = *(const short8*)(A  + (size_t)(rowA0 + r1) * Kd + k0 + s1);
        short8 b0 = *(const short8*)(Bw + (size_t)(rowB0 + r0) * Kd + k0 + s0);
        short8 b1 = *(const short8*)(Bw + (size_t)(rowB0 + r1) * Kd + k0 + s1);
        __syncthreads();
        *(short8*)&As[r0][s0] = a0;
        *(short8*)&As[r1][s1] = a1;
        *(short8*)&Bs[r0][s0] = b0;
        *(short8*)&Bs[r1][s1] = b1;
        __syncthreads();

        short8 af[4], bf[4];
#pragma unroll
        for (int m = 0; m < 4; ++m)
            af[m] = *(const short8*)&As[wr * 64 + m * 16 + fr][fq << 3];
#pragma unroll
        for (int n = 0; n < 4; ++n)
            bf[n] = *(const short8*)&Bs[wc * 64 + n * 16 + fr][fq << 3];
#pragma unroll
        for (int m = 0; m < 4; ++m)
#pragma unroll
            for (int n = 0; n < 4; ++n)
                acc[m][n] = __builtin_amdgcn_mfma_f32_16x16x32_bf16(af[m], bf[n], acc[m][n], 0, 0, 0);
    }

    const int crow0 = rowA0 + wr * 64 + (fq << 2);
    const int ccol0 = rowB0 + wc * 64 + fr;
#pragma unroll
    for (int m = 0; m < 4; ++m)
#pragma unroll
        for (int n = 0; n < 4; ++n)
#pragma unroll
            for (int j = 0; j < 4; ++j) {
                float v = acc[m][n][j];
                if (EPI) v = (v != v) ? 0.f : fminf(fmaxf(v, -1000.f), 1000.f);
                C[(size_t)(crow0 + m * 16 + j) * N + ccol0 + n * 16] = v;
            }
}

// ---------------------------------------------------------------------------
// Depthwise causal conv (K=4) + bias + SiLU on the first DI lanes of xz.
// ---------------------------------------------------------------------------
__global__ __launch_bounds__(256) void conv_silu_kernel(const float* __restrict__ xz,
                                                        const float* __restrict__ cw,
                                                        const float* __restrict__ cb,
                                                        float* __restrict__ xc)
{
    int gid = blockIdx.x * 256 + threadIdx.x;       // over B*L*DI
    int d = gid & (DIc - 1);
    int l = (gid >> 9) & (LLEN - 1);
    int b = gid >> 20;
    float s = cb[d];
#pragma unroll
    for (int k = 0; k < KCc; ++k) {
        int ls = l + k - (KCc - 1);
        if (ls >= 0)
            s += xz[((size_t)(b * LLEN + ls) << 10) + d] * cw[d * KCc + k];
    }
    xc[gid] = s * sigmoidf_(s);
}

// ---------------------------------------------------------------------------
// x_dbl[row, r] = dot(xc[row, :512], W_xproj[r, :512])   r in [0,64)
// ---------------------------------------------------------------------------
__global__ __launch_bounds__(64) void xdbl_kernel(const float* __restrict__ xc,
                                                  const float* __restrict__ Wx,
                                                  float* __restrict__ xdbl)
{
    int row = blockIdx.x;
    int r   = threadIdx.x;
    const float4* xr = (const float4*)(xc + (size_t)row * DIc);
    const float4* wr = (const float4*)(Wx + (size_t)r * DIc);
    float s = 0.f;
#pragma unroll 4
    for (int i = 0; i < DIc / 4; ++i) {
        float4 a = xr[i], w = wr[i];
        s += a.x * w.x + a.y * w.y + a.z * w.z + a.w * w.w;
    }
    xdbl[(size_t)row * NXDc + r] = s;
}

// ---------------------------------------------------------------------------
// dt[row, d] = softplus( dot(xdbl[row, :32], W_dt[d, :32]) + b_dt[d] )
// ---------------------------------------------------------------------------
__global__ __launch_bounds__(256) void dt_kernel(const float* __restrict__ xdbl,
                                                 const float* __restrict__ Wdt,
                                                 const float* __restrict__ bdt,
                                                 float* __restrict__ dt)
{
    int gid = blockIdx.x * 256 + threadIdx.x;       // over B*L*DI
    int d   = gid & (DIc - 1);
    int row = gid >> 9;
    const float4* xr = (const float4*)(xdbl + (size_t)row * NXDc);
    const float4* wr = (const float4*)(Wdt + (size_t)d * DTRc);
    float s = bdt[d];
#pragma unroll
    for (int i = 0; i < DTRc / 4; ++i) {
        float4 a = xr[i], w = wr[i];
        s += a.x * w.x + a.y * w.y + a.z * w.z + a.w * w.w;
    }
    float sp = fmaxf(s, 0.f) + log1pf(__expf(-fabsf(s)));
    dt[gid] = sp;
}

// ---------------------------------------------------------------------------
// Chunked parallel scan; chunk-state buffers overlaid on the dead x-half of xz:
//   h_end/h_in (b,c,s,d): xz[ ((b*NCH+c)*DSc + s) * 1024 + d ]   rows 0..4095
//   Sdt        (b,c,d)  : xz[ (4096 + b*NCH + c)  * 1024 + d ]   rows 4096..4351
// ---------------------------------------------------------------------------
__device__ __forceinline__ size_t hend_off(int b, int c, int s, int d) {
    return ((size_t)((b * NCH + c) * DSc + s) << 10) + d;
}
__device__ __forceinline__ size_t sdt_off(int b, int c, int d) {
    return ((size_t)(4096 + b * NCH + c) << 10) + d;
}

// Phase 1: per-(b,chunk,d) local scan with h_in = 0; emits h_end[16] and Sdt.
__global__ __launch_bounds__(256) void scan_phase1(const float* __restrict__ dty,
                                                   const float* __restrict__ xc,
                                                   const float* __restrict__ xdbl,
                                                   float* __restrict__ xzbuf,
                                                   const float* __restrict__ A_log)
{
    int half = blockIdx.x & 1;
    int c    = (blockIdx.x >> 1) & (NCH - 1);
    int b    = blockIdx.x >> 7;
    int d    = (half << 8) + threadIdx.x;

    float A[DSc];
#pragma unroll
    for (int s = 0; s < DSc; ++s) A[s] = -__expf(A_log[d * DSc + s]);

    float h[DSc];
#pragma unroll
    for (int s = 0; s < DSc; ++s) h[s] = 0.f;
    float Sdt = 0.f;

    int row0 = b * LLEN + c * CLEN;
    for (int t = 0; t < CLEN; ++t) {
        int row = row0 + t;
        float dtv = dty[((size_t)row << 9) + d];
        float xcv = xc[((size_t)row << 9) + d];
        Sdt += dtv;
        float dBx = dtv * xcv;
        const float* xd = xdbl + (size_t)row * NXDc;
#pragma unroll
        for (int s = 0; s < DSc; ++s)
            h[s] = __expf(dtv * A[s]) * h[s] + dBx * xd[DTRc + s];
    }
#pragma unroll
    for (int s = 0; s < DSc; ++s) xzbuf[hend_off(b, c, s, d)] = h[s];
    xzbuf[sdt_off(b, c, d)] = Sdt;
}

// Phase 2: per-(b,d) sequential combine over chunks; h_in overwrites h_end.
__global__ __launch_bounds__(256) void scan_phase2(float* __restrict__ xzbuf,
                                                   const float* __restrict__ A_log)
{
    int b = blockIdx.x >> 1;
    int d = ((blockIdx.x & 1) << 8) + threadIdx.x;

    float A[DSc];
#pragma unroll
    for (int s = 0; s < DSc; ++s) A[s] = -__expf(A_log[d * DSc + s]);

    float h[DSc];
#pragma unroll
    for (int s = 0; s < DSc; ++s) h[s] = 0.f;

    for (int c = 0; c < NCH; ++c) {
        float Sdt = xzbuf[sdt_off(b, c, d)];
#pragma unroll
        for (int s = 0; s < DSc; ++s) {
            size_t o = hend_off(b, c, s, d);
            float he = xzbuf[o];          // read h_end
            xzbuf[o] = h[s];              // write h_in (state before chunk c)
            h[s] = __expf(A[s] * Sdt) * h[s] + he;
        }
    }
}

// Phase 3: per-(b,chunk,d) re-scan from true h_in; writes gated y as bf16.
__global__ __launch_bounds__(256) void scan_phase3(const float* __restrict__ dty,
                                                   const float* __restrict__ xc,
                                                   const float* __restrict__ xdbl,
                                                   const float* __restrict__ xzbuf,
                                                   const float* __restrict__ A_log,
                                                   const float* __restrict__ Dp,
                                                   unsigned short* __restrict__ yb)
{
    int half = blockIdx.x & 1;
    int c    = (blockIdx.x >> 1) & (NCH - 1);
    int b    = blockIdx.x >> 7;
    int d    = (half << 8) + threadIdx.x;

    float A[DSc];
#pragma unroll
    for (int s = 0; s < DSc; ++s) A[s] = -__expf(A_log[d * DSc + s]);
    float Dv = Dp[d];

    float h[DSc];
#pragma unroll
    for (int s = 0; s < DSc; ++s) h[s] = xzbuf[hend_off(b, c, s, d)];  // h_in

    int row0 = b * LLEN + c * CLEN;
    for (int t = 0; t < CLEN; ++t) {
        int row = row0 + t;
        float dtv = dty[((size_t)row << 9) + d];
        float xcv = xc[((size_t)row << 9) + d];
        float zv  = xzbuf[((size_t)row << 10) + DIc + d];
        float dBx = dtv * xcv;
        const float* xd = xdbl + (size_t)row * NXDc;
        float acc = 0.f;
#pragma unroll
        for (int s = 0; s < DSc; ++s) {
            float dA = __expf(dtv * A[s]);
            h[s] = dA * h[s] + dBx * xd[DTRc + s];
            acc += h[s] * xd[DTRc + DSc + s];
        }
        float yv = (acc + xcv * Dv) * (zv * sigmoidf_(zv));
        yb[((size_t)row << 9) + d] = f2bf(yv);
    }
}

// ---------------------------------------------------------------------------
extern "C" void kernel_launch(void* const* d_in, const int* in_sizes, int n_in,
                              void* d_out, int out_size, void* d_ws, size_t ws_size,
                              hipStream_t stream)
{
    const float* x      = (const float*)d_in[0];
    const float* W_in   = (const float*)d_in[1];
    const float* conv_w = (const float*)d_in[2];
    const float* conv_b = (const float*)d_in[3];
    const float* W_xp   = (const float*)d_in[4];
    const float* W_dt   = (const float*)d_in[5];
    const float* b_dt   = (const float*)d_in[6];
    const float* A_log  = (const float*)d_in[7];
    const float* D_par  = (const float*)d_in[8];
    const float* W_out  = (const float*)d_in[9];
    float* out = (float*)d_out;

    float* ws   = (float*)d_ws;
    float* xz   = ws;                                   // [8192,1024] f32
    float* xc   = xz + (size_t)BLT * 1024;              // [8192,512]  f32
    float* xdbl = xc + (size_t)BLT * DIc;               // [8192,64]   f32
    float* dty  = xdbl + (size_t)BLT * NXDc;            // [8192,512]  f32 (dt)
    unsigned short* xb  = (unsigned short*)(dty + (size_t)BLT * DIc); // [8192,512] bf16 (x, then y)
    unsigned short* Wb  = xb + (size_t)BLT * DIc;       // [1024,512] bf16
    unsigned short* Wob = Wb + (size_t)1024 * DMc;      // [512,512]  bf16

    // 0. f32 -> bf16 conversions
    f32_to_bf16_kernel<<<(BLT * DMc / 8) / 256, 256, 0, stream>>>(x, xb, BLT * DMc / 8);
    f32_to_bf16_kernel<<<(1024 * DMc / 8) / 256, 256, 0, stream>>>(W_in, Wb, 1024 * DMc / 8);
    f32_to_bf16_kernel<<<(DMc * DIc / 8) / 256, 256, 0, stream>>>(W_out, Wob, DMc * DIc / 8);

    // 1. xz = x @ W_in^T      (M=8192, N=1024, K=512) via bf16 MFMA
    gemm_mfma<0><<<dim3(1024 / 128, BLT / 128), 256, 0, stream>>>(xb, Wb, xz, BLT, 1024, DMc);

    // 2. depthwise causal conv + SiLU -> xc
    conv_silu_kernel<<<(BLT * DIc) / 256, 256, 0, stream>>>(xz, conv_w, conv_b, xc);

    // 3. x_dbl = xc @ W_xproj^T   (N=64, K=512)
    xdbl_kernel<<<BLT, 64, 0, stream>>>(xc, W_xp, xdbl);

    // 4. dt = softplus(x_dbl[:, :32] @ W_dt^T + b_dt)
    dt_kernel<<<(BLT * DIc) / 256, 256, 0, stream>>>(xdbl, W_dt, b_dt, dty);

    // 5. chunked parallel scan; phase3 writes y (bf16) into xb (x no longer needed)
    scan_phase1<<<BBc * NCH * 2, 256, 0, stream>>>(dty, xc, xdbl, xz, A_log);
    scan_phase2<<<BBc * 2, 256, 0, stream>>>(xz, A_log);
    scan_phase3<<<BBc * NCH * 2, 256, 0, stream>>>(dty, xc, xdbl, xz, A_log, D_par, xb);

    // 6. out = clip(y @ W_out^T)  (M=8192, N=512, K=512) via bf16 MFMA
    gemm_mfma<1><<<dim3(DMc / 128, BLT / 128), 256, 0, stream>>>(xb, Wob, out, BLT, DMc, DMc);
}

// Round 4
// 253.315 us; speedup vs baseline: 5.9727x; 1.3411x over previous
//
#include <hip/hip_runtime.h>
#include <math.h>

// Problem constants (from reference): DM=512, DS=16, K=4, EXPAND=1
#define DMc   512
#define DIc   512
#define DSc   16
#define KCc   4
#define DTRc  32          // (512+15)//16
#define NXDc  64          // DTR + 2*DS
#define LLEN  2048
#define BBc   4
#define BLT   (BBc*LLEN)  // 8192

// chunked scan config
#define NCH   64          // chunks per sequence
#define CLEN  (LLEN/NCH)  // 32

typedef __attribute__((ext_vector_type(8))) short short8;
typedef __attribute__((ext_vector_type(8))) unsigned short ushort8;
typedef __attribute__((ext_vector_type(4))) float f32x4;

__device__ __forceinline__ float sigmoidf_(float x) { return 1.f / (1.f + __expf(-x)); }

// round-to-nearest-even f32 -> bf16 bits
__device__ __forceinline__ unsigned short f2bf(float x) {
    unsigned int u = __float_as_uint(x);
    u = (u + 0x7FFFu + ((u >> 16) & 1u)) >> 16;
    return (unsigned short)u;
}

// ---------------------------------------------------------------------------
// f32 -> bf16 elementwise (8 elems/thread), n8 = n/8
// ---------------------------------------------------------------------------
__global__ __launch_bounds__(256) void f32_to_bf16_kernel(const float* __restrict__ in,
                                                          unsigned short* __restrict__ out,
                                                          int n8)
{
    int i = blockIdx.x * 256 + threadIdx.x;
    if (i >= n8) return;
    float4 a = ((const float4*)in)[2 * i];
    float4 b = ((const float4*)in)[2 * i + 1];
    ushort8 o;
    o[0] = f2bf(a.x); o[1] = f2bf(a.y); o[2] = f2bf(a.z); o[3] = f2bf(a.w);
    o[4] = f2bf(b.x); o[5] = f2bf(b.y); o[6] = f2bf(b.z); o[7] = f2bf(b.w);
    ((ushort8*)out)[i] = o;
}

// ---------------------------------------------------------------------------
// f32 tiled GEMM: C[M,N] = A[M,K] * B[N,K]^T (both K-contiguous)
// 64x64 tile, BK=16, 256 threads, 4x4 micro-tile per thread.
// Used for the skinny x_dbl projection (N=64): 16 independent acc chains
// per thread + LDS staging beats the 1-dot-per-thread latency-bound version.
// ---------------------------------------------------------------------------
__global__ __launch_bounds__(256) void gemm_bt_f32(const float* __restrict__ A,
                                                   const float* __restrict__ Bw,
                                                   float* __restrict__ C,
                                                   int M, int N, int Kd)
{
    __shared__ float As[16][68];
    __shared__ float Bs[16][68];
    const int tid  = threadIdx.x;
    const int tx   = tid & 15;     // -> N
    const int ty   = tid >> 4;     // -> M
    const int arow = tid >> 2;     // 0..63 : row within tile for staging
    const int akq  = (tid & 3) << 2; // k offset 0,4,8,12

    const float* Ab = A  + (size_t)(blockIdx.y * 64 + arow) * Kd + akq;
    const float* Bb = Bw + (size_t)(blockIdx.x * 64 + arow) * Kd + akq;

    float acc[4][4] = {};

    for (int k0 = 0; k0 < Kd; k0 += 16) {
        float4 av = *(const float4*)(Ab + k0);
        float4 bv = *(const float4*)(Bb + k0);
        __syncthreads();
        As[akq + 0][arow] = av.x; As[akq + 1][arow] = av.y;
        As[akq + 2][arow] = av.z; As[akq + 3][arow] = av.w;
        Bs[akq + 0][arow] = bv.x; Bs[akq + 1][arow] = bv.y;
        Bs[akq + 2][arow] = bv.z; Bs[akq + 3][arow] = bv.w;
        __syncthreads();
#pragma unroll
        for (int k = 0; k < 16; ++k) {
            float4 a = *(const float4*)&As[k][ty << 2];
            float4 b = *(const float4*)&Bs[k][tx << 2];
            float ar[4] = {a.x, a.y, a.z, a.w};
            float br[4] = {b.x, b.y, b.z, b.w};
#pragma unroll
            for (int i = 0; i < 4; ++i)
#pragma unroll
                for (int j = 0; j < 4; ++j)
                    acc[i][j] += ar[i] * br[j];
        }
    }

#pragma unroll
    for (int i = 0; i < 4; ++i) {
        float4 v = make_float4(acc[i][0], acc[i][1], acc[i][2], acc[i][3]);
        *(float4*)(C + (size_t)(blockIdx.y * 64 + (ty << 2) + i) * N
                     + blockIdx.x * 64 + (tx << 2)) = v;
    }
}

// ---------------------------------------------------------------------------
// bf16 MFMA GEMM: C[M,N] = A[M,K] * B[N,K]^T, f32 accumulate/output.
// 128x128 tile, BK=32, 256 threads = 4 waves (2x2), 4x4 16x16 frags/wave.
// EPI==1: clip to [-1000,1000], NaN->0.
// ---------------------------------------------------------------------------
template<int EPI>
__global__ __launch_bounds__(256) void gemm_mfma(const unsigned short* __restrict__ A,
                                                 const unsigned short* __restrict__ Bw,
                                                 float* __restrict__ C,
                                                 int M, int N, int Kd)
{
    __shared__ short As[128][40];
    __shared__ short Bs[128][40];
    const int tid  = threadIdx.x;
    const int lane = tid & 63;
    const int wv   = tid >> 6;
    const int wr   = wv >> 1;          // wave row (0..1)
    const int wc   = wv & 1;           // wave col (0..1)
    const int fr   = lane & 15;        // fragment row within 16
    const int fq   = lane >> 4;        // k-quarter (0..3)

    const int rowA0 = blockIdx.y * 128;
    const int rowB0 = blockIdx.x * 128;

    const int r0 = tid >> 2,        s0 = (tid & 3) << 3;
    const int r1 = (tid + 256) >> 2, s1 = s0;

    f32x4 acc[4][4];
#pragma unroll
    for (int m = 0; m < 4; ++m)
#pragma unroll
        for (int n = 0; n < 4; ++n) acc[m][n] = (f32x4){0.f, 0.f, 0.f, 0.f};

    for (int k0 = 0; k0 < Kd; k0 += 32) {
        short8 a0 = *(const short8*)(A  + (size_t)(rowA0 + r0) * Kd + k0 + s0);
        short8 a1 = *(const short8*)(A  + (size_t)(rowA0 + r1) * Kd + k0 + s1);
        short8 b0 = *(const short8*)(Bw + (size_t)(rowB0 + r0) * Kd + k0 + s0);
        short8 b1 = *(const short8*)(Bw + (size_t)(rowB0 + r1) * Kd + k0 + s1);
        __syncthreads();
        *(short8*)&As[r0][s0] = a0;
        *(short8*)&As[r1][s1] = a1;
        *(short8*)&Bs[r0][s0] = b0;
        *(short8*)&Bs[r1][s1] = b1;
        __syncthreads();

        short8 af[4], bf[4];
#pragma unroll
        for (int m = 0; m < 4; ++m)
            af[m] = *(const short8*)&As[wr * 64 + m * 16 + fr][fq << 3];
#pragma unroll
        for (int n = 0; n < 4; ++n)
            bf[n] = *(const short8*)&Bs[wc * 64 + n * 16 + fr][fq << 3];
#pragma unroll
        for (int m = 0; m < 4; ++m)
#pragma unroll
            for (int n = 0; n < 4; ++n)
                acc[m][n] = __builtin_amdgcn_mfma_f32_16x16x32_bf16(af[m], bf[n], acc[m][n], 0, 0, 0);
    }

    const int crow0 = rowA0 + wr * 64 + (fq << 2);
    const int ccol0 = rowB0 + wc * 64 + fr;
#pragma unroll
    for (int m = 0; m < 4; ++m)
#pragma unroll
        for (int n = 0; n < 4; ++n)
#pragma unroll
            for (int j = 0; j < 4; ++j) {
                float v = acc[m][n][j];
                if (EPI) v = (v != v) ? 0.f : fminf(fmaxf(v, -1000.f), 1000.f);
                C[(size_t)(crow0 + m * 16 + j) * N + ccol0 + n * 16] = v;
            }
}

// ---------------------------------------------------------------------------
// Depthwise causal conv (K=4) + bias + SiLU on the first DI lanes of xz.
// ---------------------------------------------------------------------------
__global__ __launch_bounds__(256) void conv_silu_kernel(const float* __restrict__ xz,
                                                        const float* __restrict__ cw,
                                                        const float* __restrict__ cb,
                                                        float* __restrict__ xc)
{
    int gid = blockIdx.x * 256 + threadIdx.x;       // over B*L*DI
    int d = gid & (DIc - 1);
    int l = (gid >> 9) & (LLEN - 1);
    int b = gid >> 20;
    float s = cb[d];
#pragma unroll
    for (int k = 0; k < KCc; ++k) {
        int ls = l + k - (KCc - 1);
        if (ls >= 0)
            s += xz[((size_t)(b * LLEN + ls) << 10) + d] * cw[d * KCc + k];
    }
    xc[gid] = s * sigmoidf_(s);
}

// ---------------------------------------------------------------------------
// dt[row, d] = softplus( dot(xdbl[row, :32], W_dt[d, :32]) + b_dt[d] )
// ---------------------------------------------------------------------------
__global__ __launch_bounds__(256) void dt_kernel(const float* __restrict__ xdbl,
                                                 const float* __restrict__ Wdt,
                                                 const float* __restrict__ bdt,
                                                 float* __restrict__ dt)
{
    int gid = blockIdx.x * 256 + threadIdx.x;       // over B*L*DI
    int d   = gid & (DIc - 1);
    int row = gid >> 9;
    const float4* xr = (const float4*)(xdbl + (size_t)row * NXDc);
    const float4* wr = (const float4*)(Wdt + (size_t)d * DTRc);
    float s = bdt[d];
#pragma unroll
    for (int i = 0; i < DTRc / 4; ++i) {
        float4 a = xr[i], w = wr[i];
        s += a.x * w.x + a.y * w.y + a.z * w.z + a.w * w.w;
    }
    float sp = fmaxf(s, 0.f) + log1pf(__expf(-fabsf(s)));
    dt[gid] = sp;
}

// ---------------------------------------------------------------------------
// Chunked parallel scan; chunk-state buffers overlaid on the dead x-half of xz:
//   h_end/h_in (b,c,s,d): xz[ ((b*NCH+c)*DSc + s) * 1024 + d ]   rows 0..4095
//   Sdt        (b,c,d)  : xz[ (4096 + b*NCH + c)  * 1024 + d ]   rows 4096..4351
// ---------------------------------------------------------------------------
__device__ __forceinline__ size_t hend_off(int b, int c, int s, int d) {
    return ((size_t)((b * NCH + c) * DSc + s) << 10) + d;
}
__device__ __forceinline__ size_t sdt_off(int b, int c, int d) {
    return ((size_t)(4096 + b * NCH + c) << 10) + d;
}

// Phase 1: per-(b,chunk,d) local scan with h_in = 0; emits h_end[16] and Sdt.
__global__ __launch_bounds__(256) void scan_phase1(const float* __restrict__ dty,
                                                   const float* __restrict__ xc,
                                                   const float* __restrict__ xdbl,
                                                   float* __restrict__ xzbuf,
                                                   const float* __restrict__ A_log)
{
    int half = blockIdx.x & 1;
    int c    = (blockIdx.x >> 1) & (NCH - 1);
    int b    = blockIdx.x >> 7;
    int d    = (half << 8) + threadIdx.x;

    float A[DSc];
#pragma unroll
    for (int s = 0; s < DSc; ++s) A[s] = -__expf(A_log[d * DSc + s]);

    float h[DSc];
#pragma unroll
    for (int s = 0; s < DSc; ++s) h[s] = 0.f;
    float Sdt = 0.f;

    int row0 = b * LLEN + c * CLEN;
    for (int t = 0; t < CLEN; ++t) {
        int row = row0 + t;
        float dtv = dty[((size_t)row << 9) + d];
        float xcv = xc[((size_t)row << 9) + d];
        Sdt += dtv;
        float dBx = dtv * xcv;
        const float* xd = xdbl + (size_t)row * NXDc;
#pragma unroll
        for (int s = 0; s < DSc; ++s)
            h[s] = __expf(dtv * A[s]) * h[s] + dBx * xd[DTRc + s];
    }
#pragma unroll
    for (int s = 0; s < DSc; ++s) xzbuf[hend_off(b, c, s, d)] = h[s];
    xzbuf[sdt_off(b, c, d)] = Sdt;
}

// Phase 2: per-(b,d) sequential combine over chunks; h_in overwrites h_end.
__global__ __launch_bounds__(256) void scan_phase2(float* __restrict__ xzbuf,
                                                   const float* __restrict__ A_log)
{
    int b = blockIdx.x >> 1;
    int d = ((blockIdx.x & 1) << 8) + threadIdx.x;

    float A[DSc];
#pragma unroll
    for (int s = 0; s < DSc; ++s) A[s] = -__expf(A_log[d * DSc + s]);

    float h[DSc];
#pragma unroll
    for (int s = 0; s < DSc; ++s) h[s] = 0.f;

    for (int c = 0; c < NCH; ++c) {
        float Sdt = xzbuf[sdt_off(b, c, d)];
#pragma unroll
        for (int s = 0; s < DSc; ++s) {
            size_t o = hend_off(b, c, s, d);
            float he = xzbuf[o];          // read h_end
            xzbuf[o] = h[s];              // write h_in (state before chunk c)
            h[s] = __expf(A[s] * Sdt) * h[s] + he;
        }
    }
}

// Phase 3: per-(b,chunk,d) re-scan from true h_in; writes gated y as bf16.
__global__ __launch_bounds__(256) void scan_phase3(const float* __restrict__ dty,
                                                   const float* __restrict__ xc,
                                                   const float* __restrict__ xdbl,
                                                   const float* __restrict__ xzbuf,
                                                   const float* __restrict__ A_log,
                                                   const float* __restrict__ Dp,
                                                   unsigned short* __restrict__ yb)
{
    int half = blockIdx.x & 1;
    int c    = (blockIdx.x >> 1) & (NCH - 1);
    int b    = blockIdx.x >> 7;
    int d    = (half << 8) + threadIdx.x;

    float A[DSc];
#pragma unroll
    for (int s = 0; s < DSc; ++s) A[s] = -__expf(A_log[d * DSc + s]);
    float Dv = Dp[d];

    float h[DSc];
#pragma unroll
    for (int s = 0; s < DSc; ++s) h[s] = xzbuf[hend_off(b, c, s, d)];  // h_in

    int row0 = b * LLEN + c * CLEN;
    for (int t = 0; t < CLEN; ++t) {
        int row = row0 + t;
        float dtv = dty[((size_t)row << 9) + d];
        float xcv = xc[((size_t)row << 9) + d];
        float zv  = xzbuf[((size_t)row << 10) + DIc + d];
        float dBx = dtv * xcv;
        const float* xd = xdbl + (size_t)row * NXDc;
        float acc = 0.f;
#pragma unroll
        for (int s = 0; s < DSc; ++s) {
            float dA = __expf(dtv * A[s]);
            h[s] = dA * h[s] + dBx * xd[DTRc + s];
            acc += h[s] * xd[DTRc + DSc + s];
        }
        float yv = (acc + xcv * Dv) * (zv * sigmoidf_(zv));
        yb[((size_t)row << 9) + d] = f2bf(yv);
    }
}

// ---------------------------------------------------------------------------
extern "C" void kernel_launch(void* const* d_in, const int* in_sizes, int n_in,
                              void* d_out, int out_size, void* d_ws, size_t ws_size,
                              hipStream_t stream)
{
    const float* x      = (const float*)d_in[0];
    const float* W_in   = (const float*)d_in[1];
    const float* conv_w = (const float*)d_in[2];
    const float* conv_b = (const float*)d_in[3];
    const float* W_xp   = (const float*)d_in[4];
    const float* W_dt   = (const float*)d_in[5];
    const float* b_dt   = (const float*)d_in[6];
    const float* A_log  = (const float*)d_in[7];
    const float* D_par  = (const float*)d_in[8];
    const float* W_out  = (const float*)d_in[9];
    float* out = (float*)d_out;

    float* ws   = (float*)d_ws;
    float* xz   = ws;                                   // [8192,1024] f32
    float* xc   = xz + (size_t)BLT * 1024;              // [8192,512]  f32
    float* xdbl = xc + (size_t)BLT * DIc;               // [8192,64]   f32
    float* dty  = xdbl + (size_t)BLT * NXDc;            // [8192,512]  f32 (dt)
    unsigned short* xb  = (unsigned short*)(dty + (size_t)BLT * DIc); // [8192,512] bf16 (x, then y)
    unsigned short* Wb  = xb + (size_t)BLT * DIc;       // [1024,512] bf16
    unsigned short* Wob = Wb + (size_t)1024 * DMc;      // [512,512]  bf16

    // 0. f32 -> bf16 conversions
    f32_to_bf16_kernel<<<(BLT * DMc / 8) / 256, 256, 0, stream>>>(x, xb, BLT * DMc / 8);
    f32_to_bf16_kernel<<<(1024 * DMc / 8) / 256, 256, 0, stream>>>(W_in, Wb, 1024 * DMc / 8);
    f32_to_bf16_kernel<<<(DMc * DIc / 8) / 256, 256, 0, stream>>>(W_out, Wob, DMc * DIc / 8);

    // 1. xz = x @ W_in^T      (M=8192, N=1024, K=512) via bf16 MFMA
    gemm_mfma<0><<<dim3(1024 / 128, BLT / 128), 256, 0, stream>>>(xb, Wb, xz, BLT, 1024, DMc);

    // 2. depthwise causal conv + SiLU -> xc
    conv_silu_kernel<<<(BLT * DIc) / 256, 256, 0, stream>>>(xz, conv_w, conv_b, xc);

    // 3. x_dbl = xc @ W_xproj^T   (M=8192, N=64, K=512) — f32 tiled GEMM
    gemm_bt_f32<<<dim3(1, BLT / 64), 256, 0, stream>>>(xc, W_xp, xdbl, BLT, NXDc, DIc);

    // 4. dt = softplus(x_dbl[:, :32] @ W_dt^T + b_dt)
    dt_kernel<<<(BLT * DIc) / 256, 256, 0, stream>>>(xdbl, W_dt, b_dt, dty);

    // 5. chunked parallel scan; phase3 writes y (bf16) into xb (x no longer needed)
    scan_phase1<<<BBc * NCH * 2, 256, 0, stream>>>(dty, xc, xdbl, xz, A_log);
    scan_phase2<<<BBc * 2, 256, 0, stream>>>(xz, A_log);
    scan_phase3<<<BBc * NCH * 2, 256, 0, stream>>>(dty, xc, xdbl, xz, A_log, D_par, xb);

    // 6. out = clip(y @ W_out^T)  (M=8192, N=512, K=512) via bf16 MFMA
    gemm_mfma<1><<<dim3(DMc / 128, BLT / 128), 256, 0, stream>>>(xb, Wob, out, BLT, DMc, DMc);
}

// Round 5
// 195.997 us; speedup vs baseline: 7.7194x; 1.2924x over previous
//
#include <hip/hip_runtime.h>
#include <math.h>

// Problem constants (from reference): DM=512, DS=16, K=4, EXPAND=1
#define DMc   512
#define DIc   512
#define DSc   16
#define KCc   4
#define DTRc  32          // (512+15)//16
#define NXDc  64          // DTR + 2*DS
#define LLEN  2048
#define BBc   4
#define BLT   (BBc*LLEN)  // 8192

// chunked scan config
#define NCH   64          // chunks per sequence
#define CLEN  (LLEN/NCH)  // 32

typedef __attribute__((ext_vector_type(8))) short short8;
typedef __attribute__((ext_vector_type(8))) unsigned short ushort8;
typedef __attribute__((ext_vector_type(4))) float f32x4;

__device__ __forceinline__ float sigmoidf_(float x) { return 1.f / (1.f + __expf(-x)); }

// round-to-nearest-even f32 -> bf16 bits
__device__ __forceinline__ unsigned short f2bf(float x) {
    unsigned int u = __float_as_uint(x);
    u = (u + 0x7FFFu + ((u >> 16) & 1u)) >> 16;
    return (unsigned short)u;
}

// ---------------------------------------------------------------------------
// f32 -> bf16 elementwise (8 elems/thread), n8 = n/8
// ---------------------------------------------------------------------------
__global__ __launch_bounds__(256) void f32_to_bf16_kernel(const float* __restrict__ in,
                                                          unsigned short* __restrict__ out,
                                                          int n8)
{
    int i = blockIdx.x * 256 + threadIdx.x;
    if (i >= n8) return;
    float4 a = ((const float4*)in)[2 * i];
    float4 b = ((const float4*)in)[2 * i + 1];
    ushort8 o;
    o[0] = f2bf(a.x); o[1] = f2bf(a.y); o[2] = f2bf(a.z); o[3] = f2bf(a.w);
    o[4] = f2bf(b.x); o[5] = f2bf(b.y); o[6] = f2bf(b.z); o[7] = f2bf(b.w);
    ((ushort8*)out)[i] = o;
}

// ---------------------------------------------------------------------------
// f32 tiled GEMM: C[M,N] = A[M,K] * B[N,K]^T, explicit row strides lda/ldb.
// 64x64 tile, BK=16, 256 threads, 4x4 micro-tile per thread.
// EPI==0: plain store. EPI==2: v = softplus(v + bias[col]) (dt projection).
// ---------------------------------------------------------------------------
template<int EPI>
__global__ __launch_bounds__(256) void gemm_bt_f32(const float* __restrict__ A,
                                                   const float* __restrict__ Bw,
                                                   const float* __restrict__ bias,
                                                   float* __restrict__ C,
                                                   int M, int N, int Kd,
                                                   int lda, int ldb)
{
    __shared__ float As[16][68];
    __shared__ float Bs[16][68];
    const int tid  = threadIdx.x;
    const int tx   = tid & 15;     // -> N
    const int ty   = tid >> 4;     // -> M
    const int arow = tid >> 2;     // 0..63 : row within tile for staging
    const int akq  = (tid & 3) << 2; // k offset 0,4,8,12

    const float* Ab = A  + (size_t)(blockIdx.y * 64 + arow) * lda + akq;
    const float* Bb = Bw + (size_t)(blockIdx.x * 64 + arow) * ldb + akq;

    float acc[4][4] = {};

    for (int k0 = 0; k0 < Kd; k0 += 16) {
        float4 av = *(const float4*)(Ab + k0);
        float4 bv = *(const float4*)(Bb + k0);
        __syncthreads();
        As[akq + 0][arow] = av.x; As[akq + 1][arow] = av.y;
        As[akq + 2][arow] = av.z; As[akq + 3][arow] = av.w;
        Bs[akq + 0][arow] = bv.x; Bs[akq + 1][arow] = bv.y;
        Bs[akq + 2][arow] = bv.z; Bs[akq + 3][arow] = bv.w;
        __syncthreads();
#pragma unroll
        for (int k = 0; k < 16; ++k) {
            float4 a = *(const float4*)&As[k][ty << 2];
            float4 b = *(const float4*)&Bs[k][tx << 2];
            float ar[4] = {a.x, a.y, a.z, a.w};
            float br[4] = {b.x, b.y, b.z, b.w};
#pragma unroll
            for (int i = 0; i < 4; ++i)
#pragma unroll
                for (int j = 0; j < 4; ++j)
                    acc[i][j] += ar[i] * br[j];
        }
    }

    float4 bv = make_float4(0.f, 0.f, 0.f, 0.f);
    if (EPI == 2) bv = *(const float4*)(bias + blockIdx.x * 64 + (tx << 2));
#pragma unroll
    for (int i = 0; i < 4; ++i) {
        float v[4] = {acc[i][0], acc[i][1], acc[i][2], acc[i][3]};
        if (EPI == 2) {
            float bb[4] = {bv.x, bv.y, bv.z, bv.w};
#pragma unroll
            for (int j = 0; j < 4; ++j) {
                float s = v[j] + bb[j];
                v[j] = fmaxf(s, 0.f) + log1pf(__expf(-fabsf(s)));
            }
        }
        *(float4*)(C + (size_t)(blockIdx.y * 64 + (ty << 2) + i) * N
                     + blockIdx.x * 64 + (tx << 2)) = make_float4(v[0], v[1], v[2], v[3]);
    }
}

// ---------------------------------------------------------------------------
// bf16 MFMA GEMM: C[M,N] = A[M,K] * B[N,K]^T, f32 accumulate/output.
// 128x128 tile, BK=32, 256 threads = 4 waves (2x2), 4x4 16x16 frags/wave.
// EPI==1: clip to [-1000,1000], NaN->0.
// ---------------------------------------------------------------------------
template<int EPI>
__global__ __launch_bounds__(256) void gemm_mfma(const unsigned short* __restrict__ A,
                                                 const unsigned short* __restrict__ Bw,
                                                 float* __restrict__ C,
                                                 int M, int N, int Kd)
{
    __shared__ short As[128][40];
    __shared__ short Bs[128][40];
    const int tid  = threadIdx.x;
    const int lane = tid & 63;
    const int wv   = tid >> 6;
    const int wr   = wv >> 1;          // wave row (0..1)
    const int wc   = wv & 1;           // wave col (0..1)
    const int fr   = lane & 15;        // fragment row within 16
    const int fq   = lane >> 4;        // k-quarter (0..3)

    const int rowA0 = blockIdx.y * 128;
    const int rowB0 = blockIdx.x * 128;

    const int r0 = tid >> 2,        s0 = (tid & 3) << 3;
    const int r1 = (tid + 256) >> 2, s1 = s0;

    f32x4 acc[4][4];
#pragma unroll
    for (int m = 0; m < 4; ++m)
#pragma unroll
        for (int n = 0; n < 4; ++n) acc[m][n] = (f32x4){0.f, 0.f, 0.f, 0.f};

    for (int k0 = 0; k0 < Kd; k0 += 32) {
        short8 a0 = *(const short8*)(A  + (size_t)(rowA0 + r0) * Kd + k0 + s0);
        short8 a1 = *(const short8*)(A  + (size_t)(rowA0 + r1) * Kd + k0 + s1);
        short8 b0 = *(const short8*)(Bw + (size_t)(rowB0 + r0) * Kd + k0 + s0);
        short8 b1 = *(const short8*)(Bw + (size_t)(rowB0 + r1) * Kd + k0 + s1);
        __syncthreads();
        *(short8*)&As[r0][s0] = a0;
        *(short8*)&As[r1][s1] = a1;
        *(short8*)&Bs[r0][s0] = b0;
        *(short8*)&Bs[r1][s1] = b1;
        __syncthreads();

        short8 af[4], bf[4];
#pragma unroll
        for (int m = 0; m < 4; ++m)
            af[m] = *(const short8*)&As[wr * 64 + m * 16 + fr][fq << 3];
#pragma unroll
        for (int n = 0; n < 4; ++n)
            bf[n] = *(const short8*)&Bs[wc * 64 + n * 16 + fr][fq << 3];
#pragma unroll
        for (int m = 0; m < 4; ++m)
#pragma unroll
            for (int n = 0; n < 4; ++n)
                acc[m][n] = __builtin_amdgcn_mfma_f32_16x16x32_bf16(af[m], bf[n], acc[m][n], 0, 0, 0);
    }

    const int crow0 = rowA0 + wr * 64 + (fq << 2);
    const int ccol0 = rowB0 + wc * 64 + fr;
#pragma unroll
    for (int m = 0; m < 4; ++m)
#pragma unroll
        for (int n = 0; n < 4; ++n)
#pragma unroll
            for (int j = 0; j < 4; ++j) {
                float v = acc[m][n][j];
                if (EPI) v = (v != v) ? 0.f : fminf(fmaxf(v, -1000.f), 1000.f);
                C[(size_t)(crow0 + m * 16 + j) * N + ccol0 + n * 16] = v;
            }
}

// ---------------------------------------------------------------------------
// Depthwise causal conv (K=4) + bias + SiLU on the first DI lanes of xz.
// ---------------------------------------------------------------------------
__global__ __launch_bounds__(256) void conv_silu_kernel(const float* __restrict__ xz,
                                                        const float* __restrict__ cw,
                                                        const float* __restrict__ cb,
                                                        float* __restrict__ xc)
{
    int gid = blockIdx.x * 256 + threadIdx.x;       // over B*L*DI
    int d = gid & (DIc - 1);
    int l = (gid >> 9) & (LLEN - 1);
    int b = gid >> 20;
    float s = cb[d];
#pragma unroll
    for (int k = 0; k < KCc; ++k) {
        int ls = l + k - (KCc - 1);
        if (ls >= 0)
            s += xz[((size_t)(b * LLEN + ls) << 10) + d] * cw[d * KCc + k];
    }
    xc[gid] = s * sigmoidf_(s);
}

// ---------------------------------------------------------------------------
// Chunked parallel scan; chunk-state buffers overlaid on the dead x-half of xz:
//   h_end/h_in (b,c,s,d): xz[ ((b*NCH+c)*DSc + s) * 1024 + d ]   rows 0..4095
//   Sdt        (b,c,d)  : xz[ (4096 + b*NCH + c)  * 1024 + d ]   rows 4096..4351
// ---------------------------------------------------------------------------
__device__ __forceinline__ size_t hend_off(int b, int c, int s, int d) {
    return ((size_t)((b * NCH + c) * DSc + s) << 10) + d;
}
__device__ __forceinline__ size_t sdt_off(int b, int c, int d) {
    return ((size_t)(4096 + b * NCH + c) << 10) + d;
}

// Phase 1: per-(b,chunk,d) local scan with h_in = 0; emits h_end[16] and Sdt.
__global__ __launch_bounds__(256) void scan_phase1(const float* __restrict__ dty,
                                                   const float* __restrict__ xc,
                                                   const float* __restrict__ xdbl,
                                                   float* __restrict__ xzbuf,
                                                   const float* __restrict__ A_log)
{
    int half = blockIdx.x & 1;
    int c    = (blockIdx.x >> 1) & (NCH - 1);
    int b    = blockIdx.x >> 7;
    int d    = (half << 8) + threadIdx.x;

    float A[DSc];
#pragma unroll
    for (int s = 0; s < DSc; ++s) A[s] = -__expf(A_log[d * DSc + s]);

    float h[DSc];
#pragma unroll
    for (int s = 0; s < DSc; ++s) h[s] = 0.f;
    float Sdt = 0.f;

    int row0 = b * LLEN + c * CLEN;
    for (int t = 0; t < CLEN; ++t) {
        int row = row0 + t;
        float dtv = dty[((size_t)row << 9) + d];
        float xcv = xc[((size_t)row << 9) + d];
        Sdt += dtv;
        float dBx = dtv * xcv;
        const float* xd = xdbl + (size_t)row * NXDc;
#pragma unroll
        for (int s = 0; s < DSc; ++s)
            h[s] = __expf(dtv * A[s]) * h[s] + dBx * xd[DTRc + s];
    }
#pragma unroll
    for (int s = 0; s < DSc; ++s) xzbuf[hend_off(b, c, s, d)] = h[s];
    xzbuf[sdt_off(b, c, d)] = Sdt;
}

// Phase 2: per-(b,d) sequential combine over chunks; h_in overwrites h_end.
__global__ __launch_bounds__(256) void scan_phase2(float* __restrict__ xzbuf,
                                                   const float* __restrict__ A_log)
{
    int b = blockIdx.x >> 1;
    int d = ((blockIdx.x & 1) << 8) + threadIdx.x;

    float A[DSc];
#pragma unroll
    for (int s = 0; s < DSc; ++s) A[s] = -__expf(A_log[d * DSc + s]);

    float h[DSc];
#pragma unroll
    for (int s = 0; s < DSc; ++s) h[s] = 0.f;

    for (int c = 0; c < NCH; ++c) {
        float Sdt = xzbuf[sdt_off(b, c, d)];
#pragma unroll
        for (int s = 0; s < DSc; ++s) {
            size_t o = hend_off(b, c, s, d);
            float he = xzbuf[o];          // read h_end
            xzbuf[o] = h[s];              // write h_in (state before chunk c)
            h[s] = __expf(A[s] * Sdt) * h[s] + he;
        }
    }
}

// Phase 3: per-(b,chunk,d) re-scan from true h_in; writes gated y as bf16.
__global__ __launch_bounds__(256) void scan_phase3(const float* __restrict__ dty,
                                                   const float* __restrict__ xc,
                                                   const float* __restrict__ xdbl,
                                                   const float* __restrict__ xzbuf,
                                                   const float* __restrict__ A_log,
                                                   const float* __restrict__ Dp,
                                                   unsigned short* __restrict__ yb)
{
    int half = blockIdx.x & 1;
    int c    = (blockIdx.x >> 1) & (NCH - 1);
    int b    = blockIdx.x >> 7;
    int d    = (half << 8) + threadIdx.x;

    float A[DSc];
#pragma unroll
    for (int s = 0; s < DSc; ++s) A[s] = -__expf(A_log[d * DSc + s]);
    float Dv = Dp[d];

    float h[DSc];
#pragma unroll
    for (int s = 0; s < DSc; ++s) h[s] = xzbuf[hend_off(b, c, s, d)];  // h_in

    int row0 = b * LLEN + c * CLEN;
    for (int t = 0; t < CLEN; ++t) {
        int row = row0 + t;
        float dtv = dty[((size_t)row << 9) + d];
        float xcv = xc[((size_t)row << 9) + d];
        float zv  = xzbuf[((size_t)row << 10) + DIc + d];
        float dBx = dtv * xcv;
        const float* xd = xdbl + (size_t)row * NXDc;
        float acc = 0.f;
#pragma unroll
        for (int s = 0; s < DSc; ++s) {
            float dA = __expf(dtv * A[s]);
            h[s] = dA * h[s] + dBx * xd[DTRc + s];
            acc += h[s] * xd[DTRc + DSc + s];
        }
        float yv = (acc + xcv * Dv) * (zv * sigmoidf_(zv));
        yb[((size_t)row << 9) + d] = f2bf(yv);
    }
}

// ---------------------------------------------------------------------------
extern "C" void kernel_launch(void* const* d_in, const int* in_sizes, int n_in,
                              void* d_out, int out_size, void* d_ws, size_t ws_size,
                              hipStream_t stream)
{
    const float* x      = (const float*)d_in[0];
    const float* W_in   = (const float*)d_in[1];
    const float* conv_w = (const float*)d_in[2];
    const float* conv_b = (const float*)d_in[3];
    const float* W_xp   = (const float*)d_in[4];
    const float* W_dt   = (const float*)d_in[5];
    const float* b_dt   = (const float*)d_in[6];
    const float* A_log  = (const float*)d_in[7];
    const float* D_par  = (const float*)d_in[8];
    const float* W_out  = (const float*)d_in[9];
    float* out = (float*)d_out;

    float* ws   = (float*)d_ws;
    float* xz   = ws;                                   // [8192,1024] f32
    float* xc   = xz + (size_t)BLT * 1024;              // [8192,512]  f32
    float* xdbl = xc + (size_t)BLT * DIc;               // [8192,64]   f32
    float* dty  = xdbl + (size_t)BLT * NXDc;            // [8192,512]  f32 (dt)
    unsigned short* xb  = (unsigned short*)(dty + (size_t)BLT * DIc); // [8192,512] bf16 (x, then y)
    unsigned short* Wb  = xb + (size_t)BLT * DIc;       // [1024,512] bf16
    unsigned short* Wob = Wb + (size_t)1024 * DMc;      // [512,512]  bf16

    // 0. f32 -> bf16 conversions
    f32_to_bf16_kernel<<<(BLT * DMc / 8) / 256, 256, 0, stream>>>(x, xb, BLT * DMc / 8);
    f32_to_bf16_kernel<<<(1024 * DMc / 8) / 256, 256, 0, stream>>>(W_in, Wb, 1024 * DMc / 8);
    f32_to_bf16_kernel<<<(DMc * DIc / 8) / 256, 256, 0, stream>>>(W_out, Wob, DMc * DIc / 8);

    // 1. xz = x @ W_in^T      (M=8192, N=1024, K=512) via bf16 MFMA
    gemm_mfma<0><<<dim3(1024 / 128, BLT / 128), 256, 0, stream>>>(xb, Wb, xz, BLT, 1024, DMc);

    // 2. depthwise causal conv + SiLU -> xc
    conv_silu_kernel<<<(BLT * DIc) / 256, 256, 0, stream>>>(xz, conv_w, conv_b, xc);

    // 3. x_dbl = xc @ W_xproj^T   (M=8192, N=64, K=512) — f32 tiled GEMM
    gemm_bt_f32<0><<<dim3(1, BLT / 64), 256, 0, stream>>>(xc, W_xp, nullptr, xdbl,
                                                          BLT, NXDc, DIc, DIc, DIc);

    // 4. dt = softplus(x_dbl[:, :32] @ W_dt^T + b_dt)  (M=8192, N=512, K=32)
    gemm_bt_f32<2><<<dim3(DIc / 64, BLT / 64), 256, 0, stream>>>(xdbl, W_dt, b_dt, dty,
                                                                 BLT, DIc, DTRc, NXDc, DTRc);

    // 5. chunked parallel scan; phase3 writes y (bf16) into xb (x no longer needed)
    scan_phase1<<<BBc * NCH * 2, 256, 0, stream>>>(dty, xc, xdbl, xz, A_log);
    scan_phase2<<<BBc * 2, 256, 0, stream>>>(xz, A_log);
    scan_phase3<<<BBc * NCH * 2, 256, 0, stream>>>(dty, xc, xdbl, xz, A_log, D_par, xb);

    // 6. out = clip(y @ W_out^T)  (M=8192, N=512, K=512) via bf16 MFMA
    gemm_mfma<1><<<dim3(DMc / 128, BLT / 128), 256, 0, stream>>>(xb, Wob, out, BLT, DMc, DMc);
}

// Round 6
// 181.586 us; speedup vs baseline: 8.3320x; 1.0794x over previous
//
#include <hip/hip_runtime.h>
#include <math.h>

// Problem constants (from reference): DM=512, DS=16, K=4, EXPAND=1
#define DMc   512
#define DIc   512
#define DSc   16
#define KCc   4
#define DTRc  32          // (512+15)//16
#define NXDc  64          // DTR + 2*DS
#define LLEN  2048
#define BBc   4
#define BLT   (BBc*LLEN)  // 8192

// chunked scan config
#define NCH   128         // chunks per sequence
#define CLEN  (LLEN/NCH)  // 16

typedef __attribute__((ext_vector_type(8))) short short8;
typedef __attribute__((ext_vector_type(8))) unsigned short ushort8;
typedef __attribute__((ext_vector_type(4))) float f32x4;

__device__ __forceinline__ float sigmoidf_(float x) { return 1.f / (1.f + __expf(-x)); }

// round-to-nearest-even f32 -> bf16 bits
__device__ __forceinline__ unsigned short f2bf(float x) {
    unsigned int u = __float_as_uint(x);
    u = (u + 0x7FFFu + ((u >> 16) & 1u)) >> 16;
    return (unsigned short)u;
}

// ---------------------------------------------------------------------------
// fused f32 -> bf16 conversion of x, W_in, W_out (one launch, 8 elems/thread)
// ---------------------------------------------------------------------------
#define CN1 (BLT * DMc / 8)        // x
#define CN2 (1024 * DMc / 8)       // W_in
#define CN3 (DMc * DIc / 8)        // W_out
__global__ __launch_bounds__(256) void convert3_kernel(const float* __restrict__ x,
                                                       const float* __restrict__ Win,
                                                       const float* __restrict__ Wout,
                                                       unsigned short* __restrict__ xb,
                                                       unsigned short* __restrict__ Wb,
                                                       unsigned short* __restrict__ Wob)
{
    int i = blockIdx.x * 256 + threadIdx.x;
    const float* src; unsigned short* dst;
    if (i < CN1)                  { src = x;    dst = xb;  }
    else if (i < CN1 + CN2)       { src = Win;  dst = Wb;  i -= CN1; }
    else if (i < CN1 + CN2 + CN3) { src = Wout; dst = Wob; i -= CN1 + CN2; }
    else return;
    float4 a = ((const float4*)src)[2 * i];
    float4 b = ((const float4*)src)[2 * i + 1];
    ushort8 o;
    o[0] = f2bf(a.x); o[1] = f2bf(a.y); o[2] = f2bf(a.z); o[3] = f2bf(a.w);
    o[4] = f2bf(b.x); o[5] = f2bf(b.y); o[6] = f2bf(b.z); o[7] = f2bf(b.w);
    ((ushort8*)dst)[i] = o;
}

// ---------------------------------------------------------------------------
// f32 tiled GEMM: C[M,N] = A[M,K] * B[N,K]^T, explicit row strides lda/ldb.
// 64x64 tile, BK=16, 256 threads, 4x4 micro-tile per thread. (x_dbl proj)
// ---------------------------------------------------------------------------
__global__ __launch_bounds__(256) void gemm_bt_f32(const float* __restrict__ A,
                                                   const float* __restrict__ Bw,
                                                   float* __restrict__ C,
                                                   int M, int N, int Kd,
                                                   int lda, int ldb)
{
    __shared__ float As[16][68];
    __shared__ float Bs[16][68];
    const int tid  = threadIdx.x;
    const int tx   = tid & 15;     // -> N
    const int ty   = tid >> 4;     // -> M
    const int arow = tid >> 2;     // 0..63 : row within tile for staging
    const int akq  = (tid & 3) << 2; // k offset 0,4,8,12

    const float* Ab = A  + (size_t)(blockIdx.y * 64 + arow) * lda + akq;
    const float* Bb = Bw + (size_t)(blockIdx.x * 64 + arow) * ldb + akq;

    float acc[4][4] = {};

    for (int k0 = 0; k0 < Kd; k0 += 16) {
        float4 av = *(const float4*)(Ab + k0);
        float4 bv = *(const float4*)(Bb + k0);
        __syncthreads();
        As[akq + 0][arow] = av.x; As[akq + 1][arow] = av.y;
        As[akq + 2][arow] = av.z; As[akq + 3][arow] = av.w;
        Bs[akq + 0][arow] = bv.x; Bs[akq + 1][arow] = bv.y;
        Bs[akq + 2][arow] = bv.z; Bs[akq + 3][arow] = bv.w;
        __syncthreads();
#pragma unroll
        for (int k = 0; k < 16; ++k) {
            float4 a = *(const float4*)&As[k][ty << 2];
            float4 b = *(const float4*)&Bs[k][tx << 2];
            float ar[4] = {a.x, a.y, a.z, a.w};
            float br[4] = {b.x, b.y, b.z, b.w};
#pragma unroll
            for (int i = 0; i < 4; ++i)
#pragma unroll
                for (int j = 0; j < 4; ++j)
                    acc[i][j] += ar[i] * br[j];
        }
    }

#pragma unroll
    for (int i = 0; i < 4; ++i) {
        float4 v = make_float4(acc[i][0], acc[i][1], acc[i][2], acc[i][3]);
        *(float4*)(C + (size_t)(blockIdx.y * 64 + (ty << 2) + i) * N
                     + blockIdx.x * 64 + (tx << 2)) = v;
    }
}

// ---------------------------------------------------------------------------
// bf16 MFMA GEMM: C[M,N] = A[M,K] * B[N,K]^T, f32 accumulate/output.
// 128x128 tile, BK=32, 256 threads = 4 waves (2x2), 4x4 16x16 frags/wave.
// EPI==1: clip to [-1000,1000], NaN->0.
// ---------------------------------------------------------------------------
template<int EPI>
__global__ __launch_bounds__(256) void gemm_mfma(const unsigned short* __restrict__ A,
                                                 const unsigned short* __restrict__ Bw,
                                                 float* __restrict__ C,
                                                 int M, int N, int Kd)
{
    __shared__ short As[128][40];
    __shared__ short Bs[128][40];
    const int tid  = threadIdx.x;
    const int lane = tid & 63;
    const int wv   = tid >> 6;
    const int wr   = wv >> 1;          // wave row (0..1)
    const int wc   = wv & 1;           // wave col (0..1)
    const int fr   = lane & 15;        // fragment row within 16
    const int fq   = lane >> 4;        // k-quarter (0..3)

    const int rowA0 = blockIdx.y * 128;
    const int rowB0 = blockIdx.x * 128;

    const int r0 = tid >> 2,        s0 = (tid & 3) << 3;
    const int r1 = (tid + 256) >> 2, s1 = s0;

    f32x4 acc[4][4];
#pragma unroll
    for (int m = 0; m < 4; ++m)
#pragma unroll
        for (int n = 0; n < 4; ++n) acc[m][n] = (f32x4){0.f, 0.f, 0.f, 0.f};

    for (int k0 = 0; k0 < Kd; k0 += 32) {
        short8 a0 = *(const short8*)(A  + (size_t)(rowA0 + r0) * Kd + k0 + s0);
        short8 a1 = *(const short8*)(A  + (size_t)(rowA0 + r1) * Kd + k0 + s1);
        short8 b0 = *(const short8*)(Bw + (size_t)(rowB0 + r0) * Kd + k0 + s0);
        short8 b1 = *(const short8*)(Bw + (size_t)(rowB0 + r1) * Kd + k0 + s1);
        __syncthreads();
        *(short8*)&As[r0][s0] = a0;
        *(short8*)&As[r1][s1] = a1;
        *(short8*)&Bs[r0][s0] = b0;
        *(short8*)&Bs[r1][s1] = b1;
        __syncthreads();

        short8 af[4], bf[4];
#pragma unroll
        for (int m = 0; m < 4; ++m)
            af[m] = *(const short8*)&As[wr * 64 + m * 16 + fr][fq << 3];
#pragma unroll
        for (int n = 0; n < 4; ++n)
            bf[n] = *(const short8*)&Bs[wc * 64 + n * 16 + fr][fq << 3];
#pragma unroll
        for (int m = 0; m < 4; ++m)
#pragma unroll
            for (int n = 0; n < 4; ++n)
                acc[m][n] = __builtin_amdgcn_mfma_f32_16x16x32_bf16(af[m], bf[n], acc[m][n], 0, 0, 0);
    }

    const int crow0 = rowA0 + wr * 64 + (fq << 2);
    const int ccol0 = rowB0 + wc * 64 + fr;
#pragma unroll
    for (int m = 0; m < 4; ++m)
#pragma unroll
        for (int n = 0; n < 4; ++n)
#pragma unroll
            for (int j = 0; j < 4; ++j) {
                float v = acc[m][n][j];
                if (EPI) v = (v != v) ? 0.f : fminf(fmaxf(v, -1000.f), 1000.f);
                C[(size_t)(crow0 + m * 16 + j) * N + ccol0 + n * 16] = v;
            }
}

// ---------------------------------------------------------------------------
// Depthwise causal conv (K=4) + bias + SiLU on the first DI lanes of xz.
// ---------------------------------------------------------------------------
__global__ __launch_bounds__(256) void conv_silu_kernel(const float* __restrict__ xz,
                                                        const float* __restrict__ cw,
                                                        const float* __restrict__ cb,
                                                        float* __restrict__ xc)
{
    int gid = blockIdx.x * 256 + threadIdx.x;       // over B*L*DI
    int d = gid & (DIc - 1);
    int l = (gid >> 9) & (LLEN - 1);
    int b = gid >> 20;
    float s = cb[d];
#pragma unroll
    for (int k = 0; k < KCc; ++k) {
        int ls = l + k - (KCc - 1);
        if (ls >= 0)
            s += xz[((size_t)(b * LLEN + ls) << 10) + d] * cw[d * KCc + k];
    }
    xc[gid] = s * sigmoidf_(s);
}

// ---------------------------------------------------------------------------
// Chunked parallel scan with the dt-projection fused in.
// dtv(row,d) = softplus( dot(xdbl[row,0:32], W_dt[d,:]) + b_dt[d] )
// hstate[b,c,s,d] : h_end after phase1, h_in after phase2.
// ---------------------------------------------------------------------------
__device__ __forceinline__ size_t hs_off(int b, int c, int s, int d) {
    return ((size_t)((b * NCH + c) * DSc + s) << 9) + d;
}

// Phase 1: per-(b,chunk,d) local scan with h_in = 0; emits h_end[16] and Sdt.
__global__ __launch_bounds__(256) void scan_phase1(const float* __restrict__ xc,
                                                   const float* __restrict__ xdbl,
                                                   const float* __restrict__ Wdt,
                                                   const float* __restrict__ bdt,
                                                   const float* __restrict__ A_log,
                                                   float* __restrict__ hstate,
                                                   float* __restrict__ sdtbuf)
{
    int half = blockIdx.x & 1;
    int c    = (blockIdx.x >> 1) & (NCH - 1);
    int b    = blockIdx.x >> 8;
    int d    = (half << 8) + threadIdx.x;

    float A[DSc];
#pragma unroll
    for (int s = 0; s < DSc; ++s) A[s] = -__expf(A_log[d * DSc + s]);
    float wdt[DTRc];
#pragma unroll
    for (int i = 0; i < DTRc; ++i) wdt[i] = Wdt[d * DTRc + i];
    float bd = bdt[d];

    float h[DSc];
#pragma unroll
    for (int s = 0; s < DSc; ++s) h[s] = 0.f;
    float Sdt = 0.f;

    int row0 = b * LLEN + c * CLEN;
    for (int t = 0; t < CLEN; ++t) {
        int row = row0 + t;
        const float* xd = xdbl + (size_t)row * NXDc;
        float sdot = bd;
#pragma unroll
        for (int i = 0; i < DTRc; ++i) sdot += xd[i] * wdt[i];
        float dtv = fmaxf(sdot, 0.f) + log1pf(__expf(-fabsf(sdot)));
        float xcv = xc[((size_t)row << 9) + d];
        Sdt += dtv;
        float dBx = dtv * xcv;
#pragma unroll
        for (int s = 0; s < DSc; ++s)
            h[s] = __expf(dtv * A[s]) * h[s] + dBx * xd[DTRc + s];
    }
#pragma unroll
    for (int s = 0; s < DSc; ++s) hstate[hs_off(b, c, s, d)] = h[s];
    sdtbuf[((size_t)(b * NCH + c) << 9) + d] = Sdt;
}

// Phase 2: sequential combine over chunks, parallel over (b,d,s).
// h_in (state before chunk c) overwrites h_end.
__global__ __launch_bounds__(64) void scan_phase2(float* __restrict__ hstate,
                                                  const float* __restrict__ sdtbuf,
                                                  const float* __restrict__ A_log)
{
    int gid = blockIdx.x * 64 + threadIdx.x;    // over B*DSc*DIc = 32768
    int d = gid & (DIc - 1);
    int s = (gid >> 9) & (DSc - 1);
    int b = gid >> 13;

    float A = -__expf(A_log[d * DSc + s]);
    float h = 0.f;
    for (int c = 0; c < NCH; ++c) {
        size_t o = hs_off(b, c, s, d);
        float he  = hstate[o];
        float Sdt = sdtbuf[((size_t)(b * NCH + c) << 9) + d];
        hstate[o] = h;
        h = __expf(A * Sdt) * h + he;
    }
}

// Phase 3: per-(b,chunk,d) re-scan from true h_in; writes gated y as bf16.
__global__ __launch_bounds__(256) void scan_phase3(const float* __restrict__ xc,
                                                   const float* __restrict__ xdbl,
                                                   const float* __restrict__ Wdt,
                                                   const float* __restrict__ bdt,
                                                   const float* __restrict__ xzbuf,
                                                   const float* __restrict__ hstate,
                                                   const float* __restrict__ A_log,
                                                   const float* __restrict__ Dp,
                                                   unsigned short* __restrict__ yb)
{
    int half = blockIdx.x & 1;
    int c    = (blockIdx.x >> 1) & (NCH - 1);
    int b    = blockIdx.x >> 8;
    int d    = (half << 8) + threadIdx.x;

    float A[DSc];
#pragma unroll
    for (int s = 0; s < DSc; ++s) A[s] = -__expf(A_log[d * DSc + s]);
    float wdt[DTRc];
#pragma unroll
    for (int i = 0; i < DTRc; ++i) wdt[i] = Wdt[d * DTRc + i];
    float bd = bdt[d];
    float Dv = Dp[d];

    float h[DSc];
#pragma unroll
    for (int s = 0; s < DSc; ++s) h[s] = hstate[hs_off(b, c, s, d)];  // h_in

    int row0 = b * LLEN + c * CLEN;
    for (int t = 0; t < CLEN; ++t) {
        int row = row0 + t;
        const float* xd = xdbl + (size_t)row * NXDc;
        float sdot = bd;
#pragma unroll
        for (int i = 0; i < DTRc; ++i) sdot += xd[i] * wdt[i];
        float dtv = fmaxf(sdot, 0.f) + log1pf(__expf(-fabsf(sdot)));
        float xcv = xc[((size_t)row << 9) + d];
        float zv  = xzbuf[((size_t)row << 10) + DIc + d];
        float dBx = dtv * xcv;
        float acc = 0.f;
#pragma unroll
        for (int s = 0; s < DSc; ++s) {
            float dA = __expf(dtv * A[s]);
            h[s] = dA * h[s] + dBx * xd[DTRc + s];
            acc += h[s] * xd[DTRc + DSc + s];
        }
        float yv = (acc + xcv * Dv) * (zv * sigmoidf_(zv));
        yb[((size_t)row << 9) + d] = f2bf(yv);
    }
}

// ---------------------------------------------------------------------------
extern "C" void kernel_launch(void* const* d_in, const int* in_sizes, int n_in,
                              void* d_out, int out_size, void* d_ws, size_t ws_size,
                              hipStream_t stream)
{
    const float* x      = (const float*)d_in[0];
    const float* W_in   = (const float*)d_in[1];
    const float* conv_w = (const float*)d_in[2];
    const float* conv_b = (const float*)d_in[3];
    const float* W_xp   = (const float*)d_in[4];
    const float* W_dt   = (const float*)d_in[5];
    const float* b_dt   = (const float*)d_in[6];
    const float* A_log  = (const float*)d_in[7];
    const float* D_par  = (const float*)d_in[8];
    const float* W_out  = (const float*)d_in[9];
    float* out = (float*)d_out;

    float* ws   = (float*)d_ws;
    float* xz   = ws;                                   // [8192,1024] f32
    float* xc   = xz + (size_t)BLT * 1024;              // [8192,512]  f32
    float* xdbl = xc + (size_t)BLT * DIc;               // [8192,64]   f32
    unsigned short* xb  = (unsigned short*)(xdbl + (size_t)BLT * NXDc); // [8192,512] bf16 (x, then y)
    unsigned short* Wb  = xb + (size_t)BLT * DIc;       // [1024,512] bf16
    unsigned short* Wob = Wb + (size_t)1024 * DMc;      // [512,512]  bf16
    float* hstate = (float*)(Wob + (size_t)DMc * DIc);  // [4,128,16,512] f32
    float* sdtbuf = hstate + (size_t)BBc * NCH * DSc * DIc; // [4,128,512] f32

    // 0. f32 -> bf16 conversions (x, W_in, W_out) in one launch
    convert3_kernel<<<(CN1 + CN2 + CN3 + 255) / 256, 256, 0, stream>>>(
        x, W_in, W_out, xb, Wb, Wob);

    // 1. xz = x @ W_in^T      (M=8192, N=1024, K=512) via bf16 MFMA
    gemm_mfma<0><<<dim3(1024 / 128, BLT / 128), 256, 0, stream>>>(xb, Wb, xz, BLT, 1024, DMc);

    // 2. depthwise causal conv + SiLU -> xc
    conv_silu_kernel<<<(BLT * DIc) / 256, 256, 0, stream>>>(xz, conv_w, conv_b, xc);

    // 3. x_dbl = xc @ W_xproj^T   (M=8192, N=64, K=512) — f32 tiled GEMM
    gemm_bt_f32<<<dim3(1, BLT / 64), 256, 0, stream>>>(xc, W_xp, xdbl,
                                                       BLT, NXDc, DIc, DIc, DIc);

    // 4+5. chunked parallel scan with fused dt projection; y (bf16) into xb
    scan_phase1<<<BBc * NCH * 2, 256, 0, stream>>>(xc, xdbl, W_dt, b_dt, A_log,
                                                   hstate, sdtbuf);
    scan_phase2<<<(BBc * DSc * DIc) / 64, 64, 0, stream>>>(hstate, sdtbuf, A_log);
    scan_phase3<<<BBc * NCH * 2, 256, 0, stream>>>(xc, xdbl, W_dt, b_dt, xz,
                                                   hstate, A_log, D_par, xb);

    // 6. out = clip(y @ W_out^T)  (M=8192, N=512, K=512) via bf16 MFMA
    gemm_mfma<1><<<dim3(DMc / 128, BLT / 128), 256, 0, stream>>>(xb, Wob, out, BLT, DMc, DMc);
}

// Round 7
// 169.629 us; speedup vs baseline: 8.9193x; 1.0705x over previous
//
#include <hip/hip_runtime.h>
#include <math.h>

// Problem constants (from reference): DM=512, DS=16, K=4, EXPAND=1
#define DMc   512
#define DIc   512
#define DSc   16
#define KCc   4
#define DTRc  32          // (512+15)//16
#define NXDc  64          // DTR + 2*DS
#define LLEN  2048
#define BBc   4
#define BLT   (BBc*LLEN)  // 8192

// chunked scan config
#define NCH   128         // chunks per sequence
#define CLEN  (LLEN/NCH)  // 16

typedef __attribute__((ext_vector_type(8))) short short8;
typedef __attribute__((ext_vector_type(8))) unsigned short ushort8;
typedef __attribute__((ext_vector_type(4))) float f32x4;

__device__ __forceinline__ float sigmoidf_(float x) { return 1.f / (1.f + __expf(-x)); }

// round-to-nearest-even f32 -> bf16 bits
__device__ __forceinline__ unsigned short f2bf(float x) {
    unsigned int u = __float_as_uint(x);
    u = (u + 0x7FFFu + ((u >> 16) & 1u)) >> 16;
    return (unsigned short)u;
}

// ---------------------------------------------------------------------------
// fused f32 -> bf16 conversion of x, W_in, W_out (one launch, 8 elems/thread)
// ---------------------------------------------------------------------------
#define CN1 (BLT * DMc / 8)        // x
#define CN2 (1024 * DMc / 8)       // W_in
#define CN3 (DMc * DIc / 8)        // W_out
__global__ __launch_bounds__(256) void convert3_kernel(const float* __restrict__ x,
                                                       const float* __restrict__ Win,
                                                       const float* __restrict__ Wout,
                                                       unsigned short* __restrict__ xb,
                                                       unsigned short* __restrict__ Wb,
                                                       unsigned short* __restrict__ Wob)
{
    int i = blockIdx.x * 256 + threadIdx.x;
    const float* src; unsigned short* dst;
    if (i < CN1)                  { src = x;    dst = xb;  }
    else if (i < CN1 + CN2)       { src = Win;  dst = Wb;  i -= CN1; }
    else if (i < CN1 + CN2 + CN3) { src = Wout; dst = Wob; i -= CN1 + CN2; }
    else return;
    float4 a = ((const float4*)src)[2 * i];
    float4 b = ((const float4*)src)[2 * i + 1];
    ushort8 o;
    o[0] = f2bf(a.x); o[1] = f2bf(a.y); o[2] = f2bf(a.z); o[3] = f2bf(a.w);
    o[4] = f2bf(b.x); o[5] = f2bf(b.y); o[6] = f2bf(b.z); o[7] = f2bf(b.w);
    ((ushort8*)dst)[i] = o;
}

// ---------------------------------------------------------------------------
// f32 tiled GEMM: C[M,N] = A[M,K] * B[N,K]^T, strides lda/ldb/ldc.
// 64x64 tile, BK=16, 256 threads, 4x4 micro-tile per thread.
// EPI==0: plain. EPI==2: v = softplus(v + bias[col]) (dt projection).
// ---------------------------------------------------------------------------
template<int EPI>
__global__ __launch_bounds__(256) void gemm_bt_f32(const float* __restrict__ A,
                                                   const float* __restrict__ Bw,
                                                   const float* __restrict__ bias,
                                                   float* __restrict__ C,
                                                   int M, int N, int Kd,
                                                   int lda, int ldb, int ldc)
{
    __shared__ float As[16][68];
    __shared__ float Bs[16][68];
    const int tid  = threadIdx.x;
    const int tx   = tid & 15;     // -> N
    const int ty   = tid >> 4;     // -> M
    const int arow = tid >> 2;     // 0..63 : row within tile for staging
    const int akq  = (tid & 3) << 2; // k offset 0,4,8,12

    const float* Ab = A  + (size_t)(blockIdx.y * 64 + arow) * lda + akq;
    const float* Bb = Bw + (size_t)(blockIdx.x * 64 + arow) * ldb + akq;

    float acc[4][4] = {};

    for (int k0 = 0; k0 < Kd; k0 += 16) {
        float4 av = *(const float4*)(Ab + k0);
        float4 bv = *(const float4*)(Bb + k0);
        __syncthreads();
        As[akq + 0][arow] = av.x; As[akq + 1][arow] = av.y;
        As[akq + 2][arow] = av.z; As[akq + 3][arow] = av.w;
        Bs[akq + 0][arow] = bv.x; Bs[akq + 1][arow] = bv.y;
        Bs[akq + 2][arow] = bv.z; Bs[akq + 3][arow] = bv.w;
        __syncthreads();
#pragma unroll
        for (int k = 0; k < 16; ++k) {
            float4 a = *(const float4*)&As[k][ty << 2];
            float4 b = *(const float4*)&Bs[k][tx << 2];
            float ar[4] = {a.x, a.y, a.z, a.w};
            float br[4] = {b.x, b.y, b.z, b.w};
#pragma unroll
            for (int i = 0; i < 4; ++i)
#pragma unroll
                for (int j = 0; j < 4; ++j)
                    acc[i][j] += ar[i] * br[j];
        }
    }

    float4 bv = make_float4(0.f, 0.f, 0.f, 0.f);
    if (EPI == 2) bv = *(const float4*)(bias + blockIdx.x * 64 + (tx << 2));
#pragma unroll
    for (int i = 0; i < 4; ++i) {
        float v[4] = {acc[i][0], acc[i][1], acc[i][2], acc[i][3]};
        if (EPI == 2) {
            float bb[4] = {bv.x, bv.y, bv.z, bv.w};
#pragma unroll
            for (int j = 0; j < 4; ++j) {
                float s = v[j] + bb[j];
                v[j] = fmaxf(s, 0.f) + log1pf(__expf(-fabsf(s)));
            }
        }
        *(float4*)(C + (size_t)(blockIdx.y * 64 + (ty << 2) + i) * ldc
                     + blockIdx.x * 64 + (tx << 2)) = make_float4(v[0], v[1], v[2], v[3]);
    }
}

// ---------------------------------------------------------------------------
// bf16 MFMA GEMM: C[M,N] = A[M,K] * B[N,K]^T, f32 accumulate/output.
// 128x128 tile, BK=32, 256 threads = 4 waves (2x2), 4x4 16x16 frags/wave.
// EPI==1: clip to [-1000,1000], NaN->0.
// ---------------------------------------------------------------------------
template<int EPI>
__global__ __launch_bounds__(256) void gemm_mfma(const unsigned short* __restrict__ A,
                                                 const unsigned short* __restrict__ Bw,
                                                 float* __restrict__ C,
                                                 int M, int N, int Kd)
{
    __shared__ short As[128][40];
    __shared__ short Bs[128][40];
    const int tid  = threadIdx.x;
    const int lane = tid & 63;
    const int wv   = tid >> 6;
    const int wr   = wv >> 1;          // wave row (0..1)
    const int wc   = wv & 1;           // wave col (0..1)
    const int fr   = lane & 15;        // fragment row within 16
    const int fq   = lane >> 4;        // k-quarter (0..3)

    const int rowA0 = blockIdx.y * 128;
    const int rowB0 = blockIdx.x * 128;

    const int r0 = tid >> 2,        s0 = (tid & 3) << 3;
    const int r1 = (tid + 256) >> 2, s1 = s0;

    f32x4 acc[4][4];
#pragma unroll
    for (int m = 0; m < 4; ++m)
#pragma unroll
        for (int n = 0; n < 4; ++n) acc[m][n] = (f32x4){0.f, 0.f, 0.f, 0.f};

    for (int k0 = 0; k0 < Kd; k0 += 32) {
        short8 a0 = *(const short8*)(A  + (size_t)(rowA0 + r0) * Kd + k0 + s0);
        short8 a1 = *(const short8*)(A  + (size_t)(rowA0 + r1) * Kd + k0 + s1);
        short8 b0 = *(const short8*)(Bw + (size_t)(rowB0 + r0) * Kd + k0 + s0);
        short8 b1 = *(const short8*)(Bw + (size_t)(rowB0 + r1) * Kd + k0 + s1);
        __syncthreads();
        *(short8*)&As[r0][s0] = a0;
        *(short8*)&As[r1][s1] = a1;
        *(short8*)&Bs[r0][s0] = b0;
        *(short8*)&Bs[r1][s1] = b1;
        __syncthreads();

        short8 af[4], bf[4];
#pragma unroll
        for (int m = 0; m < 4; ++m)
            af[m] = *(const short8*)&As[wr * 64 + m * 16 + fr][fq << 3];
#pragma unroll
        for (int n = 0; n < 4; ++n)
            bf[n] = *(const short8*)&Bs[wc * 64 + n * 16 + fr][fq << 3];
#pragma unroll
        for (int m = 0; m < 4; ++m)
#pragma unroll
            for (int n = 0; n < 4; ++n)
                acc[m][n] = __builtin_amdgcn_mfma_f32_16x16x32_bf16(af[m], bf[n], acc[m][n], 0, 0, 0);
    }

    const int crow0 = rowA0 + wr * 64 + (fq << 2);
    const int ccol0 = rowB0 + wc * 64 + fr;
#pragma unroll
    for (int m = 0; m < 4; ++m)
#pragma unroll
        for (int n = 0; n < 4; ++n)
#pragma unroll
            for (int j = 0; j < 4; ++j) {
                float v = acc[m][n][j];
                if (EPI) v = (v != v) ? 0.f : fminf(fmaxf(v, -1000.f), 1000.f);
                C[(size_t)(crow0 + m * 16 + j) * N + ccol0 + n * 16] = v;
            }
}

// ---------------------------------------------------------------------------
// Depthwise causal conv (K=4) + bias + SiLU on the first DI lanes of xz.
// ---------------------------------------------------------------------------
__global__ __launch_bounds__(256) void conv_silu_kernel(const float* __restrict__ xz,
                                                        const float* __restrict__ cw,
                                                        const float* __restrict__ cb,
                                                        float* __restrict__ xc)
{
    int gid = blockIdx.x * 256 + threadIdx.x;       // over B*L*DI
    int d = gid & (DIc - 1);
    int l = (gid >> 9) & (LLEN - 1);
    int b = gid >> 20;
    float s = cb[d];
#pragma unroll
    for (int k = 0; k < KCc; ++k) {
        int ls = l + k - (KCc - 1);
        if (ls >= 0)
            s += xz[((size_t)(b * LLEN + ls) << 10) + d] * cw[d * KCc + k];
    }
    xc[gid] = s * sigmoidf_(s);
}

// ---------------------------------------------------------------------------
// Chunked parallel scan. dt precomputed by GEMM into the dead x-half of xz
// (dtz[row*1024 + d]); z lives at dtz[row*1024 + 512 + d].
// hstate[b,c,s,d]: h_end after phase1, h_in after phase2.
// Latency strategy: register-preload the thread's whole chunk of dt/xc/z in
// one burst; stage the chunk's B/C slice (xdbl[row][32:64]) in LDS; fully
// unroll the t-loop so the serial chain is pure VALU + LDS broadcasts.
// ---------------------------------------------------------------------------
__device__ __forceinline__ size_t hs_off(int b, int c, int s, int d) {
    return ((size_t)((b * NCH + c) * DSc + s) << 9) + d;
}

// Phase 1: per-(b,chunk,d) local scan with h_in = 0; emits h_end[16] and Sdt.
__global__ __launch_bounds__(256) void scan_phase1(const float* __restrict__ dtz,
                                                   const float* __restrict__ xc,
                                                   const float* __restrict__ xdbl,
                                                   const float* __restrict__ A_log,
                                                   float* __restrict__ hstate,
                                                   float* __restrict__ sdtbuf)
{
    int half = blockIdx.x & 1;
    int c    = (blockIdx.x >> 1) & (NCH - 1);
    int b    = blockIdx.x >> 8;
    int d    = (half << 8) + threadIdx.x;
    int row0 = b * LLEN + c * CLEN;

    __shared__ float bc[CLEN][32];   // [t][0:16]=B, [t][16:32]=C (C unused here)
    {
        int r = threadIdx.x >> 4, col = (threadIdx.x & 15) << 1;
        const float* src = xdbl + (size_t)(row0 + r) * NXDc + DTRc + col;
        bc[r][col] = src[0]; bc[r][col + 1] = src[1];
    }

    float A[DSc];
#pragma unroll
    for (int s = 0; s < DSc; ++s) A[s] = -__expf(A_log[d * DSc + s]);

    float dtv[CLEN], xcv[CLEN];
#pragma unroll
    for (int t = 0; t < CLEN; ++t) {
        dtv[t] = dtz[((size_t)(row0 + t) << 10) + d];
        xcv[t] = xc [((size_t)(row0 + t) << 9) + d];
    }
    __syncthreads();

    float h[DSc] = {};
    float Sdt = 0.f;
#pragma unroll
    for (int t = 0; t < CLEN; ++t) {
        float dBx = dtv[t] * xcv[t];
        Sdt += dtv[t];
#pragma unroll
        for (int s = 0; s < DSc; ++s)
            h[s] = __expf(dtv[t] * A[s]) * h[s] + dBx * bc[t][s];
    }
#pragma unroll
    for (int s = 0; s < DSc; ++s) hstate[hs_off(b, c, s, d)] = h[s];
    sdtbuf[((size_t)(b * NCH + c) << 9) + d] = Sdt;
}

// Phase 2: sequential combine over chunks, parallel over (b,d,s).
// h_in (state before chunk c) overwrites h_end.
__global__ __launch_bounds__(64) void scan_phase2(float* __restrict__ hstate,
                                                  const float* __restrict__ sdtbuf,
                                                  const float* __restrict__ A_log)
{
    int gid = blockIdx.x * 64 + threadIdx.x;    // over B*DSc*DIc = 32768
    int d = gid & (DIc - 1);
    int s = (gid >> 9) & (DSc - 1);
    int b = gid >> 13;

    float A = -__expf(A_log[d * DSc + s]);
    float h = 0.f;
    for (int c = 0; c < NCH; ++c) {
        size_t o = hs_off(b, c, s, d);
        float he  = hstate[o];
        float Sdt = sdtbuf[((size_t)(b * NCH + c) << 9) + d];
        hstate[o] = h;
        h = __expf(A * Sdt) * h + he;
    }
}

// Phase 3: per-(b,chunk,d) re-scan from true h_in; writes gated y as bf16.
__global__ __launch_bounds__(256) void scan_phase3(const float* __restrict__ dtz,
                                                   const float* __restrict__ xc,
                                                   const float* __restrict__ xdbl,
                                                   const float* __restrict__ hstate,
                                                   const float* __restrict__ A_log,
                                                   const float* __restrict__ Dp,
                                                   unsigned short* __restrict__ yb)
{
    int half = blockIdx.x & 1;
    int c    = (blockIdx.x >> 1) & (NCH - 1);
    int b    = blockIdx.x >> 8;
    int d    = (half << 8) + threadIdx.x;
    int row0 = b * LLEN + c * CLEN;

    __shared__ float bc[CLEN][32];   // [t][0:16]=B, [t][16:32]=C
    {
        int r = threadIdx.x >> 4, col = (threadIdx.x & 15) << 1;
        const float* src = xdbl + (size_t)(row0 + r) * NXDc + DTRc + col;
        bc[r][col] = src[0]; bc[r][col + 1] = src[1];
    }

    float A[DSc];
#pragma unroll
    for (int s = 0; s < DSc; ++s) A[s] = -__expf(A_log[d * DSc + s]);
    float Dv = Dp[d];

    float dtv[CLEN], xcv[CLEN], zv[CLEN];
#pragma unroll
    for (int t = 0; t < CLEN; ++t) {
        dtv[t] = dtz[((size_t)(row0 + t) << 10) + d];
        xcv[t] = xc [((size_t)(row0 + t) << 9) + d];
        zv[t]  = dtz[((size_t)(row0 + t) << 10) + DIc + d];
    }

    float h[DSc];
#pragma unroll
    for (int s = 0; s < DSc; ++s) h[s] = hstate[hs_off(b, c, s, d)];  // h_in
    __syncthreads();

#pragma unroll
    for (int t = 0; t < CLEN; ++t) {
        float dBx = dtv[t] * xcv[t];
        float acc = 0.f;
#pragma unroll
        for (int s = 0; s < DSc; ++s) {
            float dA = __expf(dtv[t] * A[s]);
            h[s] = dA * h[s] + dBx * bc[t][s];
            acc += h[s] * bc[t][DSc + s];
        }
        float yv = (acc + xcv[t] * Dv) * (zv[t] * sigmoidf_(zv[t]));
        yb[((size_t)(row0 + t) << 9) + d] = f2bf(yv);
    }
}

// ---------------------------------------------------------------------------
extern "C" void kernel_launch(void* const* d_in, const int* in_sizes, int n_in,
                              void* d_out, int out_size, void* d_ws, size_t ws_size,
                              hipStream_t stream)
{
    const float* x      = (const float*)d_in[0];
    const float* W_in   = (const float*)d_in[1];
    const float* conv_w = (const float*)d_in[2];
    const float* conv_b = (const float*)d_in[3];
    const float* W_xp   = (const float*)d_in[4];
    const float* W_dt   = (const float*)d_in[5];
    const float* b_dt   = (const float*)d_in[6];
    const float* A_log  = (const float*)d_in[7];
    const float* D_par  = (const float*)d_in[8];
    const float* W_out  = (const float*)d_in[9];
    float* out = (float*)d_out;

    float* ws   = (float*)d_ws;
    float* xz   = ws;                                   // [8192,1024] f32; after conv, cols 0..511 reused for dt
    float* xc   = xz + (size_t)BLT * 1024;              // [8192,512]  f32
    float* xdbl = xc + (size_t)BLT * DIc;               // [8192,64]   f32
    unsigned short* xb  = (unsigned short*)(xdbl + (size_t)BLT * NXDc); // [8192,512] bf16 (x, then y)
    unsigned short* Wb  = xb + (size_t)BLT * DIc;       // [1024,512] bf16
    unsigned short* Wob = Wb + (size_t)1024 * DMc;      // [512,512]  bf16
    float* hstate = (float*)(Wob + (size_t)DMc * DIc);  // [4,128,16,512] f32
    float* sdtbuf = hstate + (size_t)BBc * NCH * DSc * DIc; // [4,128,512] f32

    // 0. f32 -> bf16 conversions (x, W_in, W_out) in one launch
    convert3_kernel<<<(CN1 + CN2 + CN3 + 255) / 256, 256, 0, stream>>>(
        x, W_in, W_out, xb, Wb, Wob);

    // 1. xz = x @ W_in^T      (M=8192, N=1024, K=512) via bf16 MFMA
    gemm_mfma<0><<<dim3(1024 / 128, BLT / 128), 256, 0, stream>>>(xb, Wb, xz, BLT, 1024, DMc);

    // 2. depthwise causal conv + SiLU -> xc
    conv_silu_kernel<<<(BLT * DIc) / 256, 256, 0, stream>>>(xz, conv_w, conv_b, xc);

    // 3. x_dbl = xc @ W_xproj^T   (M=8192, N=64, K=512)
    gemm_bt_f32<0><<<dim3(1, BLT / 64), 256, 0, stream>>>(xc, W_xp, nullptr, xdbl,
                                                          BLT, NXDc, DIc, DIc, DIc, NXDc);

    // 4. dt = softplus(x_dbl[:, :32] @ W_dt^T + b_dt) -> dead x-half of xz (ldc=1024)
    gemm_bt_f32<2><<<dim3(DIc / 64, BLT / 64), 256, 0, stream>>>(xdbl, W_dt, b_dt, xz,
                                                                 BLT, DIc, DTRc, NXDc, DTRc, 1024);

    // 5. chunked parallel scan; y (bf16) into xb
    scan_phase1<<<BBc * NCH * 2, 256, 0, stream>>>(xz, xc, xdbl, A_log, hstate, sdtbuf);
    scan_phase2<<<(BBc * DSc * DIc) / 64, 64, 0, stream>>>(hstate, sdtbuf, A_log);
    scan_phase3<<<BBc * NCH * 2, 256, 0, stream>>>(xz, xc, xdbl, hstate, A_log, D_par, xb);

    // 6. out = clip(y @ W_out^T)  (M=8192, N=512, K=512) via bf16 MFMA
    gemm_mfma<1><<<dim3(DMc / 128, BLT / 128), 256, 0, stream>>>(xb, Wob, out, BLT, DMc, DMc);
}